// Round 1
// baseline (1111.409 us; speedup 1.0000x reference)
//
#include <hip/hip_runtime.h>

#define N 8192
#define F 500
#define NH 256
#define CAP (1 << 17)   // edge capacity (expected ~tens of edges)

// ---------------- init ----------------
__global__ void init_kernel(float* deg, float* psum, unsigned* tmax, unsigned* cnt) {
    int i = blockIdx.x * 256 + threadIdx.x;
    if (i < N) deg[i] = 1.0f;              // self-loops
    if (i < 3 * NH) psum[i] = 0.0f;
    if (i == 0) { *tmax = 0u; *cnt = 0u; }
}

// ---------------- sq norms ----------------
__global__ void sqnorm_kernel(const float* __restrict__ X, float* __restrict__ sq) {
    __shared__ float red[256];
    int row = blockIdx.x;
    const float* x = X + (size_t)row * F;
    float s = 0.f;
    for (int k = threadIdx.x; k < F; k += 256) { float v = x[k]; s += v * v; }
    red[threadIdx.x] = s;
    __syncthreads();
    for (int off = 128; off > 0; off >>= 1) {
        if (threadIdx.x < off) red[threadIdx.x] += red[threadIdx.x + off];
        __syncthreads();
    }
    if (threadIdx.x == 0) sq[row] = red[0];
}

// ---------------- pairwise distance passes ----------------
// PASS==1: global max of d (upper triangle).  PASS==2: emit edges d<t, bump deg.
template <int PASS>
__global__ __launch_bounds__(256) void dist_kernel(const float* __restrict__ X,
                                                   const float* __restrict__ sq,
                                                   unsigned* __restrict__ tmax,
                                                   unsigned* __restrict__ cnt,
                                                   int2* __restrict__ edges,
                                                   float* __restrict__ deg) {
    constexpr int NB = N / 64;  // 128
    int L = blockIdx.x;
    // decode upper-triangular block pair (bi <= bj); start(b) = b*NB - b*(b-1)/2
    float a = (float)(2 * NB + 1);
    int bi = (int)((a - sqrtf(a * a - 8.0f * (float)L)) * 0.5f);
    if (bi < 0) bi = 0;
    if (bi > NB - 1) bi = NB - 1;
    while (bi > 0 && bi * NB - bi * (bi - 1) / 2 > L) --bi;
    while (bi < NB - 1 && (bi + 1) * NB - (bi + 1) * bi / 2 <= L) ++bi;
    int bj = bi + (L - (bi * NB - bi * (bi - 1) / 2));

    __shared__ float As[16][68];
    __shared__ float Bs[16][68];
    __shared__ float wred[4];

    int tid = threadIdx.x;
    int tx = tid & 15, ty = tid >> 4;
    int ro = ty * 4, co = tx * 4;
    int li = tid >> 2;           // 0..63 row-in-tile for staging
    int lk = (tid & 3) << 2;     // 0,4,8,12 k-offset for staging

    const float* Arow = X + (size_t)(bi * 64 + li) * F;
    const float* Brow = X + (size_t)(bj * 64 + li) * F;

    float acc[4][4] = {{0.f}};

    for (int kc = 0; kc < F; kc += 16) {
        int k0 = kc + lk;
        float4 av = make_float4(0.f, 0.f, 0.f, 0.f);
        float4 bv = make_float4(0.f, 0.f, 0.f, 0.f);
        if (k0 + 4 <= F) {  // F%4==0, so float4 chunks are cleanly valid/invalid
            av = *(const float4*)(Arow + k0);
            bv = *(const float4*)(Brow + k0);
        }
        __syncthreads();
        As[lk + 0][li] = av.x; As[lk + 1][li] = av.y; As[lk + 2][li] = av.z; As[lk + 3][li] = av.w;
        Bs[lk + 0][li] = bv.x; Bs[lk + 1][li] = bv.y; Bs[lk + 2][li] = bv.z; Bs[lk + 3][li] = bv.w;
        __syncthreads();
#pragma unroll
        for (int k = 0; k < 16; k++) {
            float4 a4 = *(const float4*)&As[k][ro];
            float4 b4 = *(const float4*)&Bs[k][co];
            acc[0][0] += a4.x * b4.x; acc[0][1] += a4.x * b4.y; acc[0][2] += a4.x * b4.z; acc[0][3] += a4.x * b4.w;
            acc[1][0] += a4.y * b4.x; acc[1][1] += a4.y * b4.y; acc[1][2] += a4.y * b4.z; acc[1][3] += a4.y * b4.w;
            acc[2][0] += a4.z * b4.x; acc[2][1] += a4.z * b4.y; acc[2][2] += a4.z * b4.z; acc[2][3] += a4.z * b4.w;
            acc[3][0] += a4.w * b4.x; acc[3][1] += a4.w * b4.y; acc[3][2] += a4.w * b4.z; acc[3][3] += a4.w * b4.w;
        }
    }

    int gi = bi * 64 + ro, gj = bj * 64 + co;
    if (PASS == 1) {
        float m = 0.f;  // d >= 0 up to rounding; clamp at 0 keeps bit-compare max valid
#pragma unroll
        for (int r = 0; r < 4; r++) {
            float si = sq[gi + r];
#pragma unroll
            for (int c = 0; c < 4; c++) {
                int j = gj + c;
                if (j > gi + r) {
                    float d = si + sq[j] - 2.0f * acc[r][c];
                    m = fmaxf(m, d);
                }
            }
        }
        for (int off = 32; off > 0; off >>= 1) m = fmaxf(m, __shfl_down(m, off, 64));
        if ((tid & 63) == 0) wred[tid >> 6] = m;
        __syncthreads();
        if (tid == 0) {
            m = fmaxf(fmaxf(wred[0], wred[1]), fmaxf(wred[2], wred[3]));
            atomicMax(tmax, __float_as_uint(m));
        }
    } else {
        float t = 0.5f * __uint_as_float(*tmax);
#pragma unroll
        for (int r = 0; r < 4; r++) {
            int i = gi + r;
            float si = sq[i];
#pragma unroll
            for (int c = 0; c < 4; c++) {
                int j = gj + c;
                if (j > i) {
                    float d = si + sq[j] - 2.0f * acc[r][c];
                    if (d < t) {
                        unsigned p = atomicAdd(cnt, 1u);
                        if (p < (unsigned)CAP) edges[p] = make_int2(i, j);
                        atomicAdd(&deg[j], 1.0f);
                    }
                }
            }
        }
    }
}

// ---------------- dinv ----------------
__global__ void dinv_kernel(const float* __restrict__ deg, float* __restrict__ dinv) {
    int i = blockIdx.x * 256 + threadIdx.x;
    if (i < N) dinv[i] = 1.0f / sqrtf(deg[i]);
}

// ---------------- f32 GEMM: C[M][NH] = A[M][K] @ B[K][NH] ----------------
__global__ __launch_bounds__(256) void gemm_kernel(const float* __restrict__ A,
                                                   const float* __restrict__ B,
                                                   float* __restrict__ C, int K) {
    __shared__ float As[16][68];
    __shared__ float Bs[16][68];
    int bm = blockIdx.x, bn = blockIdx.y;
    int tid = threadIdx.x;
    int tx = tid & 15, ty = tid >> 4;
    int ro = ty * 4, co = tx * 4;
    int li = tid >> 2, lk = (tid & 3) << 2;     // A staging: 64 rows x 16 k
    int lkb = tid >> 4, lnb = (tid & 15) << 2;  // B staging: 16 k rows x 64 n

    const float* Arow = A + (size_t)(bm * 64 + li) * K;
    float acc[4][4] = {{0.f}};

    for (int kc = 0; kc < K; kc += 16) {
        int k0 = kc + lk;
        float4 av = make_float4(0.f, 0.f, 0.f, 0.f);
        if (k0 + 4 <= K) av = *(const float4*)(Arow + k0);
        float4 bv = make_float4(0.f, 0.f, 0.f, 0.f);
        int kb = kc + lkb;
        if (kb < K) bv = *(const float4*)(B + (size_t)kb * NH + bn * 64 + lnb);
        __syncthreads();
        As[lk + 0][li] = av.x; As[lk + 1][li] = av.y; As[lk + 2][li] = av.z; As[lk + 3][li] = av.w;
        *(float4*)&Bs[lkb][lnb] = bv;
        __syncthreads();
#pragma unroll
        for (int k = 0; k < 16; k++) {
            float4 a4 = *(const float4*)&As[k][ro];
            float4 b4 = *(const float4*)&Bs[k][co];
            acc[0][0] += a4.x * b4.x; acc[0][1] += a4.x * b4.y; acc[0][2] += a4.x * b4.z; acc[0][3] += a4.x * b4.w;
            acc[1][0] += a4.y * b4.x; acc[1][1] += a4.y * b4.y; acc[1][2] += a4.y * b4.z; acc[1][3] += a4.y * b4.w;
            acc[2][0] += a4.z * b4.x; acc[2][1] += a4.z * b4.y; acc[2][2] += a4.z * b4.z; acc[2][3] += a4.z * b4.w;
            acc[3][0] += a4.w * b4.x; acc[3][1] += a4.w * b4.y; acc[3][2] += a4.w * b4.z; acc[3][3] += a4.w * b4.w;
        }
    }
    int gm = bm * 64 + ro, gn = bn * 64 + co;
#pragma unroll
    for (int r = 0; r < 4; r++) {
        float4 v = make_float4(acc[r][0], acc[r][1], acc[r][2], acc[r][3]);
        *(float4*)&C[(size_t)(gm + r) * NH + gn] = v;
    }
}

// ---------------- sparse aggregation ----------------
// Z[i][f] = dinv[i]^2 * H[i][f]   (self-loop term)
__global__ void selfagg_kernel(const float* __restrict__ H, const float* __restrict__ dinv,
                               float* __restrict__ Z) {
    int i = blockIdx.x;
    int f = threadIdx.x;
    float w = dinv[i] * dinv[i];
    Z[(size_t)i * NH + f] = w * H[(size_t)i * NH + f];
}

// Z[j][f] += dinv[i]*dinv[j]*H[i][f] for each edge (i,j), i<j
__global__ void edgeagg_kernel(const float* __restrict__ H, const float* __restrict__ dinv,
                               const int2* __restrict__ edges, const unsigned* __restrict__ cnt,
                               float* __restrict__ Z) {
    unsigned n = *cnt;
    if (n > (unsigned)CAP) n = CAP;
    int f = threadIdx.x;
    for (unsigned e = blockIdx.x; e < n; e += gridDim.x) {
        int2 ij = edges[e];
        float w = dinv[ij.x] * dinv[ij.y];
        atomicAdd(&Z[(size_t)ij.y * NH + f], w * H[(size_t)ij.x * NH + f]);
    }
}

// x = relu(Z + b) in place; accumulate column sums into psum
__global__ void relupool_kernel(float* __restrict__ Z, const float* __restrict__ b,
                                float* __restrict__ psum) {
    int f = threadIdx.x;
    int i0 = blockIdx.x * 64;
    float bias = b[f];
    float s = 0.f;
    for (int r = 0; r < 64; r++) {
        size_t idx = (size_t)(i0 + r) * NH + f;
        float v = Z[idx] + bias;
        v = fmaxf(v, 0.f);
        Z[idx] = v;
        s += v;
    }
    atomicAdd(&psum[f], s);
}

// out[f] = out[f+NH] = (psum0+psum1+psum2)[f] / N
__global__ void finalize_kernel(const float* __restrict__ psum, float* __restrict__ out) {
    int f = threadIdx.x;
    float p = (psum[f] + psum[NH + f] + psum[2 * NH + f]) * (1.0f / (float)N);
    out[f] = p;
    out[NH + f] = p;
}

static inline size_t align_up(size_t x, size_t a) { return (x + a - 1) & ~(a - 1); }

extern "C" void kernel_launch(void* const* d_in, const int* in_sizes, int n_in,
                              void* d_out, int out_size, void* d_ws, size_t ws_size,
                              hipStream_t stream) {
    const float* feature = (const float*)d_in[0];
    const float* W1 = (const float*)d_in[1];
    const float* b1 = (const float*)d_in[2];
    const float* W2 = (const float*)d_in[3];
    const float* b2 = (const float*)d_in[4];
    const float* W3 = (const float*)d_in[5];
    const float* b3 = (const float*)d_in[6];
    float* out = (float*)d_out;

    // workspace layout
    char* w = (char*)d_ws;
    size_t off = 0;
    float* sq = (float*)(w + off);      off += (size_t)N * 4;
    float* deg = (float*)(w + off);     off += (size_t)N * 4;
    float* dinv = (float*)(w + off);    off += (size_t)N * 4;
    float* psum = (float*)(w + off);    off += 3 * NH * 4;
    unsigned* tmax = (unsigned*)(w + off); off += 4;
    unsigned* cnt = (unsigned*)(w + off);  off += 4;
    off = align_up(off, 256);
    int2* edges = (int2*)(w + off);     off += (size_t)CAP * 8;
    off = align_up(off, 256);
    float* B0 = (float*)(w + off);      off += (size_t)N * NH * 4;
    float* B1 = (float*)(w + off);      off += (size_t)N * NH * 4;

    constexpr int NB = N / 64;
    constexpr int TRI_BLOCKS = NB * (NB + 1) / 2;  // 8256

    init_kernel<<<N / 256, 256, 0, stream>>>(deg, psum, tmax, cnt);
    sqnorm_kernel<<<N, 256, 0, stream>>>(feature, sq);
    dist_kernel<1><<<TRI_BLOCKS, 256, 0, stream>>>(feature, sq, tmax, cnt, edges, deg);
    dist_kernel<2><<<TRI_BLOCKS, 256, 0, stream>>>(feature, sq, tmax, cnt, edges, deg);
    dinv_kernel<<<N / 256, 256, 0, stream>>>(deg, dinv);

    // layer 1: H = feature @ W1 ; Z = A*H ; x1 = relu(Z+b1) (in B1)
    gemm_kernel<<<dim3(NB, NH / 64), 256, 0, stream>>>(feature, W1, B0, F);
    selfagg_kernel<<<N, NH, 0, stream>>>(B0, dinv, B1);
    edgeagg_kernel<<<256, NH, 0, stream>>>(B0, dinv, edges, cnt, B1);
    relupool_kernel<<<N / 64, NH, 0, stream>>>(B1, b1, psum);

    // layer 2
    gemm_kernel<<<dim3(NB, NH / 64), 256, 0, stream>>>(B1, W2, B0, NH);
    selfagg_kernel<<<N, NH, 0, stream>>>(B0, dinv, B1);
    edgeagg_kernel<<<256, NH, 0, stream>>>(B0, dinv, edges, cnt, B1);
    relupool_kernel<<<N / 64, NH, 0, stream>>>(B1, b2, psum + NH);

    // layer 3
    gemm_kernel<<<dim3(NB, NH / 64), 256, 0, stream>>>(B1, W3, B0, NH);
    selfagg_kernel<<<N, NH, 0, stream>>>(B0, dinv, B1);
    edgeagg_kernel<<<256, NH, 0, stream>>>(B0, dinv, edges, cnt, B1);
    relupool_kernel<<<N / 64, NH, 0, stream>>>(B1, b3, psum + 2 * NH);

    finalize_kernel<<<1, NH, 0, stream>>>(psum, out);
}

// Round 2
// 419.379 us; speedup vs baseline: 2.6501x; 2.6501x over previous
//
#include <hip/hip_runtime.h>

#define N 8192
#define F 500
#define K2 512                      // F padded to MFMA-friendly K
#define NH 256
#define CAP (1 << 17)               // edge capacity (expected ~tens of edges)
#define BT 128                      // dist tile
#define NBT (N / BT)                // 64
#define TRI2 (NBT * (NBT + 1) / 2)  // 2080
#define PITCH 72                    // LDS row pitch (bf16 elems): 144B = 16B-aligned, bank-friendly
#define KSTEP 64

using bf16x8 = __attribute__((ext_vector_type(8))) short;
using f32x4  = __attribute__((ext_vector_type(4))) float;

__device__ __forceinline__ unsigned short f32_to_bf16(float x) {
    unsigned u = __float_as_uint(x);
    u += 0x7fffu + ((u >> 16) & 1u);   // RTNE
    return (unsigned short)(u >> 16);
}
__device__ __forceinline__ float bf16_to_f32(unsigned short h) {
    return __uint_as_float(((unsigned)h) << 16);
}

// ---------------- init ----------------
__global__ void init_kernel(float* deg, float* psum, unsigned* tmax, unsigned* cnt) {
    int i = blockIdx.x * 256 + threadIdx.x;
    if (i < N) deg[i] = 1.0f;              // self-loops
    if (i < 3 * NH) psum[i] = 0.0f;
    if (i == 0) { *tmax = 0u; *cnt = 0u; }
}

// ---------------- split f32 -> bf16 hi/lo, pad K to 512 ----------------
__global__ void convert_kernel(const float* __restrict__ X, unsigned short* __restrict__ Xh,
                               unsigned short* __restrict__ Xl) {
    int i = blockIdx.x;
    for (int k = threadIdx.x; k < K2; k += 256) {
        float x = (k < F) ? X[(size_t)i * F + k] : 0.f;
        unsigned short h = f32_to_bf16(x);
        float r = x - bf16_to_f32(h);
        unsigned short l = f32_to_bf16(r);
        Xh[(size_t)i * K2 + k] = h;
        Xl[(size_t)i * K2 + k] = l;
    }
}

// ---------------- sq norms (f32, exact) ----------------
__global__ void sqnorm_kernel(const float* __restrict__ X, float* __restrict__ sq) {
    __shared__ float red[256];
    int row = blockIdx.x;
    const float* x = X + (size_t)row * F;
    float s = 0.f;
    for (int k = threadIdx.x; k < F; k += 256) { float v = x[k]; s += v * v; }
    red[threadIdx.x] = s;
    __syncthreads();
    for (int off = 128; off > 0; off >>= 1) {
        if (threadIdx.x < off) red[threadIdx.x] += red[threadIdx.x + off];
        __syncthreads();
    }
    if (threadIdx.x == 0) sq[row] = red[0];
}

// ---------------- MFMA pairwise-distance passes ----------------
// PASS==1: per-block {max,min} of d (upper triangle); global max via atomic.
// PASS==2: skip block if blockmin >= t, else recompute (bit-identical) and emit edges.
template <int PASS>
__global__ __launch_bounds__(256) void dist2_kernel(const unsigned short* __restrict__ Xh,
                                                    const unsigned short* __restrict__ Xl,
                                                    const float* __restrict__ sq,
                                                    unsigned* __restrict__ tmax,
                                                    float* __restrict__ blockmin,
                                                    unsigned* __restrict__ cnt,
                                                    int2* __restrict__ edges,
                                                    float* __restrict__ deg) {
    int L = blockIdx.x;
    // decode upper-triangular block pair (bi <= bj); start(b) = b*NBT - b*(b-1)/2
    float a = (float)(2 * NBT + 1);
    int bi = (int)((a - sqrtf(a * a - 8.0f * (float)L)) * 0.5f);
    if (bi < 0) bi = 0;
    if (bi > NBT - 1) bi = NBT - 1;
    while (bi > 0 && bi * NBT - bi * (bi - 1) / 2 > L) --bi;
    while (bi < NBT - 1 && (bi + 1) * NBT - (bi + 1) * bi / 2 <= L) ++bi;
    int bj = bi + (L - (bi * NBT - bi * (bi - 1) / 2));

    float t = 0.f;
    if (PASS == 2) {
        t = 0.5f * __uint_as_float(*tmax);
        if (!(blockmin[L] < t)) return;   // no edge in this block (exact complement of pass-1 min)
    }

    __shared__ __align__(16) unsigned short Ah[BT][PITCH];
    __shared__ __align__(16) unsigned short Al[BT][PITCH];
    __shared__ __align__(16) unsigned short Bh[BT][PITCH];
    __shared__ __align__(16) unsigned short Bl[BT][PITCH];
    __shared__ float wmaxs[4], wmins[4];

    int tid = threadIdx.x;
    int w = tid >> 6;                 // wave 0..3 -> 2x2 grid of 64x64 sub-tiles
    int wm = w >> 1, wn = w & 1;
    int lane = tid & 63;
    int lr = lane & 15;               // fragment row/col index
    int lk = (lane >> 4) << 3;        // fragment k offset: 0,8,16,24

    int gi0 = bi * BT, gj0 = bj * BT;

    f32x4 acc[4][4] = {};

    for (int kc = 0; kc < K2; kc += KSTEP) {
        __syncthreads();
#pragma unroll
        for (int it = 0; it < 4; ++it) {
            int c = tid + it * 256;
            int row = c >> 3, k8 = (c & 7) << 3;
            size_t ga = (size_t)(gi0 + row) * K2 + kc + k8;
            size_t gb = (size_t)(gj0 + row) * K2 + kc + k8;
            *(bf16x8*)&Ah[row][k8] = *(const bf16x8*)&Xh[ga];
            *(bf16x8*)&Al[row][k8] = *(const bf16x8*)&Xl[ga];
            *(bf16x8*)&Bh[row][k8] = *(const bf16x8*)&Xh[gb];
            *(bf16x8*)&Bl[row][k8] = *(const bf16x8*)&Xl[gb];
        }
        __syncthreads();
#pragma unroll
        for (int ks = 0; ks < 2; ++ks) {
            int ko = ks * 32 + lk;
            bf16x8 ahf[4], alf[4], bhf[4], blf[4];
#pragma unroll
            for (int mf = 0; mf < 4; ++mf) {
                int r = wm * 64 + mf * 16 + lr;
                ahf[mf] = *(const bf16x8*)&Ah[r][ko];
                alf[mf] = *(const bf16x8*)&Al[r][ko];
            }
#pragma unroll
            for (int nf = 0; nf < 4; ++nf) {
                int r = wn * 64 + nf * 16 + lr;
                bhf[nf] = *(const bf16x8*)&Bh[r][ko];
                blf[nf] = *(const bf16x8*)&Bl[r][ko];
            }
#pragma unroll
            for (int mf = 0; mf < 4; ++mf)
#pragma unroll
                for (int nf = 0; nf < 4; ++nf) {
                    acc[mf][nf] = __builtin_amdgcn_mfma_f32_16x16x32_bf16(ahf[mf], bhf[nf], acc[mf][nf], 0, 0, 0);
                    acc[mf][nf] = __builtin_amdgcn_mfma_f32_16x16x32_bf16(ahf[mf], blf[nf], acc[mf][nf], 0, 0, 0);
                    acc[mf][nf] = __builtin_amdgcn_mfma_f32_16x16x32_bf16(alf[mf], bhf[nf], acc[mf][nf], 0, 0, 0);
                }
        }
    }

    // epilogue: C/D layout col = lane&15, row = (lane>>4)*4 + reg
    int gi = gi0 + wm * 64, gj = gj0 + wn * 64;
    int rbase = (lane >> 4) << 2;
    if (PASS == 1) {
        float mmax = 0.f, mmin = 3e38f;
#pragma unroll
        for (int mf = 0; mf < 4; ++mf)
#pragma unroll
            for (int nf = 0; nf < 4; ++nf)
#pragma unroll
                for (int r = 0; r < 4; ++r) {
                    int i = gi + mf * 16 + rbase + r;
                    int j = gj + nf * 16 + lr;
                    if (j > i) {
                        float d = sq[i] + sq[j] - 2.0f * acc[mf][nf][r];
                        mmax = fmaxf(mmax, d);
                        mmin = fminf(mmin, d);
                    }
                }
        for (int off = 32; off > 0; off >>= 1) {
            mmax = fmaxf(mmax, __shfl_xor(mmax, off, 64));
            mmin = fminf(mmin, __shfl_xor(mmin, off, 64));
        }
        if (lane == 0) { wmaxs[w] = mmax; wmins[w] = mmin; }
        __syncthreads();
        if (tid == 0) {
            float M = fmaxf(fmaxf(wmaxs[0], wmaxs[1]), fmaxf(wmaxs[2], wmaxs[3]));
            float m = fminf(fminf(wmins[0], wmins[1]), fminf(wmins[2], wmins[3]));
            atomicMax(tmax, __float_as_uint(M));   // d >= 0, bit-compare valid
            blockmin[L] = m;
        }
    } else {
#pragma unroll
        for (int mf = 0; mf < 4; ++mf)
#pragma unroll
            for (int nf = 0; nf < 4; ++nf)
#pragma unroll
                for (int r = 0; r < 4; ++r) {
                    int i = gi + mf * 16 + rbase + r;
                    int j = gj + nf * 16 + lr;
                    if (j > i) {
                        float d = sq[i] + sq[j] - 2.0f * acc[mf][nf][r];
                        if (d < t) {
                            unsigned p = atomicAdd(cnt, 1u);
                            if (p < (unsigned)CAP) edges[p] = make_int2(i, j);
                            atomicAdd(&deg[j], 1.0f);
                        }
                    }
                }
    }
}

// ---------------- dinv ----------------
__global__ void dinv_kernel(const float* __restrict__ deg, float* __restrict__ dinv) {
    int i = blockIdx.x * 256 + threadIdx.x;
    if (i < N) dinv[i] = 1.0f / sqrtf(deg[i]);
}

// ---------------- f32 GEMM: C[M][NH] = A[M][K] @ B[K][NH] ----------------
__global__ __launch_bounds__(256) void gemm_kernel(const float* __restrict__ A,
                                                   const float* __restrict__ B,
                                                   float* __restrict__ C, int K) {
    __shared__ float As[16][68];
    __shared__ float Bs[16][68];
    int bm = blockIdx.x, bn = blockIdx.y;
    int tid = threadIdx.x;
    int tx = tid & 15, ty = tid >> 4;
    int ro = ty * 4, co = tx * 4;
    int li = tid >> 2, lk = (tid & 3) << 2;     // A staging: 64 rows x 16 k
    int lkb = tid >> 4, lnb = (tid & 15) << 2;  // B staging: 16 k rows x 64 n

    const float* Arow = A + (size_t)(bm * 64 + li) * K;
    float acc[4][4] = {{0.f}};

    for (int kc = 0; kc < K; kc += 16) {
        int k0 = kc + lk;
        float4 av = make_float4(0.f, 0.f, 0.f, 0.f);
        if (k0 + 4 <= K) av = *(const float4*)(Arow + k0);
        float4 bv = make_float4(0.f, 0.f, 0.f, 0.f);
        int kb = kc + lkb;
        if (kb < K) bv = *(const float4*)(B + (size_t)kb * NH + bn * 64 + lnb);
        __syncthreads();
        As[lk + 0][li] = av.x; As[lk + 1][li] = av.y; As[lk + 2][li] = av.z; As[lk + 3][li] = av.w;
        *(float4*)&Bs[lkb][lnb] = bv;
        __syncthreads();
#pragma unroll
        for (int k = 0; k < 16; k++) {
            float4 a4 = *(const float4*)&As[k][ro];
            float4 b4 = *(const float4*)&Bs[k][co];
            acc[0][0] += a4.x * b4.x; acc[0][1] += a4.x * b4.y; acc[0][2] += a4.x * b4.z; acc[0][3] += a4.x * b4.w;
            acc[1][0] += a4.y * b4.x; acc[1][1] += a4.y * b4.y; acc[1][2] += a4.y * b4.z; acc[1][3] += a4.y * b4.w;
            acc[2][0] += a4.z * b4.x; acc[2][1] += a4.z * b4.y; acc[2][2] += a4.z * b4.z; acc[2][3] += a4.z * b4.w;
            acc[3][0] += a4.w * b4.x; acc[3][1] += a4.w * b4.y; acc[3][2] += a4.w * b4.z; acc[3][3] += a4.w * b4.w;
        }
    }
    int gm = bm * 64 + ro, gn = bn * 64 + co;
#pragma unroll
    for (int r = 0; r < 4; r++) {
        float4 v = make_float4(acc[r][0], acc[r][1], acc[r][2], acc[r][3]);
        *(float4*)&C[(size_t)(gm + r) * NH + gn] = v;
    }
}

// ---------------- sparse aggregation ----------------
__global__ void selfagg_kernel(const float* __restrict__ H, const float* __restrict__ dinv,
                               float* __restrict__ Z) {
    int i = blockIdx.x;
    int f = threadIdx.x;
    float w = dinv[i] * dinv[i];
    Z[(size_t)i * NH + f] = w * H[(size_t)i * NH + f];
}

__global__ void edgeagg_kernel(const float* __restrict__ H, const float* __restrict__ dinv,
                               const int2* __restrict__ edges, const unsigned* __restrict__ cnt,
                               float* __restrict__ Z) {
    unsigned n = *cnt;
    if (n > (unsigned)CAP) n = CAP;
    int f = threadIdx.x;
    for (unsigned e = blockIdx.x; e < n; e += gridDim.x) {
        int2 ij = edges[e];
        float w = dinv[ij.x] * dinv[ij.y];
        atomicAdd(&Z[(size_t)ij.y * NH + f], w * H[(size_t)ij.x * NH + f]);
    }
}

__global__ void relupool_kernel(float* __restrict__ Z, const float* __restrict__ b,
                                float* __restrict__ psum) {
    int f = threadIdx.x;
    int i0 = blockIdx.x * 64;
    float bias = b[f];
    float s = 0.f;
    for (int r = 0; r < 64; r++) {
        size_t idx = (size_t)(i0 + r) * NH + f;
        float v = Z[idx] + bias;
        v = fmaxf(v, 0.f);
        Z[idx] = v;
        s += v;
    }
    atomicAdd(&psum[f], s);
}

__global__ void finalize_kernel(const float* __restrict__ psum, float* __restrict__ out) {
    int f = threadIdx.x;
    float p = (psum[f] + psum[NH + f] + psum[2 * NH + f]) * (1.0f / (float)N);
    out[f] = p;
    out[NH + f] = p;
}

static inline size_t align_up(size_t x, size_t a) { return (x + a - 1) & ~(a - 1); }

extern "C" void kernel_launch(void* const* d_in, const int* in_sizes, int n_in,
                              void* d_out, int out_size, void* d_ws, size_t ws_size,
                              hipStream_t stream) {
    const float* feature = (const float*)d_in[0];
    const float* W1 = (const float*)d_in[1];
    const float* b1 = (const float*)d_in[2];
    const float* W2 = (const float*)d_in[3];
    const float* b2 = (const float*)d_in[4];
    const float* W3 = (const float*)d_in[5];
    const float* b3 = (const float*)d_in[6];
    float* out = (float*)d_out;

    // workspace layout
    char* w = (char*)d_ws;
    size_t off = 0;
    float* sq = (float*)(w + off);        off += (size_t)N * 4;
    float* deg = (float*)(w + off);       off += (size_t)N * 4;
    float* dinv = (float*)(w + off);      off += (size_t)N * 4;
    float* psum = (float*)(w + off);      off += 3 * NH * 4;
    unsigned* tmax = (unsigned*)(w + off); off += 4;
    unsigned* cnt = (unsigned*)(w + off);  off += 4;
    off = align_up(off, 256);
    float* blockmin = (float*)(w + off);  off += (size_t)TRI2 * 4;
    off = align_up(off, 256);
    int2* edges = (int2*)(w + off);       off += (size_t)CAP * 8;
    off = align_up(off, 256);
    float* B0 = (float*)(w + off);        off += (size_t)N * NH * 4;
    float* B1 = (float*)(w + off);        off += (size_t)N * NH * 4;
    off = align_up(off, 256);
    unsigned short* Xh = (unsigned short*)(w + off); off += (size_t)N * K2 * 2;
    unsigned short* Xl = (unsigned short*)(w + off); off += (size_t)N * K2 * 2;

    init_kernel<<<N / 256, 256, 0, stream>>>(deg, psum, tmax, cnt);
    convert_kernel<<<N, 256, 0, stream>>>(feature, Xh, Xl);
    sqnorm_kernel<<<N, 256, 0, stream>>>(feature, sq);
    dist2_kernel<1><<<TRI2, 256, 0, stream>>>(Xh, Xl, sq, tmax, blockmin, cnt, edges, deg);
    dist2_kernel<2><<<TRI2, 256, 0, stream>>>(Xh, Xl, sq, tmax, blockmin, cnt, edges, deg);
    dinv_kernel<<<N / 256, 256, 0, stream>>>(deg, dinv);

    constexpr int NB64 = N / 64;

    // layer 1
    gemm_kernel<<<dim3(NB64, NH / 64), 256, 0, stream>>>(feature, W1, B0, F);
    selfagg_kernel<<<N, NH, 0, stream>>>(B0, dinv, B1);
    edgeagg_kernel<<<256, NH, 0, stream>>>(B0, dinv, edges, cnt, B1);
    relupool_kernel<<<N / 64, NH, 0, stream>>>(B1, b1, psum);

    // layer 2
    gemm_kernel<<<dim3(NB64, NH / 64), 256, 0, stream>>>(B1, W2, B0, NH);
    selfagg_kernel<<<N, NH, 0, stream>>>(B0, dinv, B1);
    edgeagg_kernel<<<256, NH, 0, stream>>>(B0, dinv, edges, cnt, B1);
    relupool_kernel<<<N / 64, NH, 0, stream>>>(B1, b2, psum + NH);

    // layer 3
    gemm_kernel<<<dim3(NB64, NH / 64), 256, 0, stream>>>(B1, W3, B0, NH);
    selfagg_kernel<<<N, NH, 0, stream>>>(B0, dinv, B1);
    edgeagg_kernel<<<256, NH, 0, stream>>>(B0, dinv, edges, cnt, B1);
    relupool_kernel<<<N / 64, NH, 0, stream>>>(B1, b3, psum + 2 * NH);

    finalize_kernel<<<1, NH, 0, stream>>>(psum, out);
}

// Round 3
// 237.455 us; speedup vs baseline: 4.6805x; 1.7661x over previous
//
#include <hip/hip_runtime.h>

#define N 8192
#define F 500
#define K2 512                      // F padded to MFMA-friendly K
#define NH 256
#define CAP (1 << 17)
#define BT 128                      // dist tile
#define NBT (N / BT)                // 64
#define TRI2 (NBT * (NBT + 1) / 2)  // 2080
#define KS 32                       // K-step

using bf16x8 = __attribute__((ext_vector_type(8))) short;
using f32x4  = __attribute__((ext_vector_type(4))) float;

__device__ __forceinline__ unsigned short f32_to_bf16(float x) {
    unsigned u = __float_as_uint(x);
    u += 0x7fffu + ((u >> 16) & 1u);   // RTNE
    return (unsigned short)(u >> 16);
}
__device__ __forceinline__ float bf16_to_f32(unsigned short h) {
    return __uint_as_float(((unsigned)h) << 16);
}

// swizzled LDS fragment read: plane is [128 rows][32 bf16] linear (64 B rows)
__device__ __forceinline__ bf16x8 frag_ld(const unsigned short* plane, int r, int k2b) {
    int k2 = k2b ^ (((r >> 1) & 3) << 4);
    return *(const bf16x8*)((const char*)plane + r * 64 + k2);
}

// ---------------- init ----------------
__global__ void init_kernel(float* deg, float* psum, unsigned* tmax, unsigned* cnt) {
    int i = blockIdx.x * 256 + threadIdx.x;
    if (i < N) deg[i] = 1.0f;
    if (i < 3 * NH) psum[i] = 0.0f;
    if (i == 0) { *tmax = 0u; *cnt = 0u; }
}

// ---------------- split f32 -> bf16 hi/lo (pad K to 512) + sq norms ----------------
__global__ void prep_kernel(const float* __restrict__ X, unsigned short* __restrict__ Xh,
                            unsigned short* __restrict__ Xl, float* __restrict__ sq) {
    __shared__ float red[256];
    int i = blockIdx.x;
    float s = 0.f;
    for (int k = threadIdx.x; k < K2; k += 256) {
        float x = (k < F) ? X[(size_t)i * F + k] : 0.f;
        unsigned short h = f32_to_bf16(x);
        float r = x - bf16_to_f32(h);
        Xh[(size_t)i * K2 + k] = h;
        Xl[(size_t)i * K2 + k] = f32_to_bf16(r);
        s += x * x;
    }
    red[threadIdx.x] = s;
    __syncthreads();
    for (int off = 128; off > 0; off >>= 1) {
        if (threadIdx.x < off) red[threadIdx.x] += red[threadIdx.x + off];
        __syncthreads();
    }
    if (threadIdx.x == 0) sq[i] = red[0];
}

// ---------------- W[K][256] f32 -> Wt[256][Kp] bf16 (transposed, zero-pad) ----------------
__global__ void wconv_kernel(const float* __restrict__ W, unsigned short* __restrict__ Wt,
                             int K, int Kp) {
    int n = blockIdx.x;
    for (int k = threadIdx.x; k < Kp; k += 256) {
        float v = (k < K) ? W[(size_t)k * NH + n] : 0.f;
        Wt[(size_t)n * Kp + k] = f32_to_bf16(v);
    }
}

// ---------------- MFMA pairwise-distance passes (m97-style staging) ----------------
template <int PASS>
__global__ __launch_bounds__(256) void dist3_kernel(const unsigned short* __restrict__ Xh,
                                                    const unsigned short* __restrict__ Xl,
                                                    const float* __restrict__ sq,
                                                    unsigned* __restrict__ tmax,
                                                    float* __restrict__ blockmin,
                                                    unsigned* __restrict__ cnt,
                                                    int2* __restrict__ edges,
                                                    float* __restrict__ deg) {
    // XCD-aware swizzle: 2080 % 8 == 0, bijective
    int L = (blockIdx.x % 8) * (TRI2 / 8) + blockIdx.x / 8;
    // decode upper-triangular block pair (bi <= bj)
    float a = (float)(2 * NBT + 1);
    int bi = (int)((a - sqrtf(a * a - 8.0f * (float)L)) * 0.5f);
    if (bi < 0) bi = 0;
    if (bi > NBT - 1) bi = NBT - 1;
    while (bi > 0 && bi * NBT - bi * (bi - 1) / 2 > L) --bi;
    while (bi < NBT - 1 && (bi + 1) * NBT - (bi + 1) * bi / 2 <= L) ++bi;
    int bj = bi + (L - (bi * NBT - bi * (bi - 1) / 2));

    float t = 0.f;
    if (PASS == 2) {
        t = 0.5f * __uint_as_float(*tmax);
        if (!(blockmin[L] < t)) return;
    }

    __shared__ __align__(16) unsigned short planes[4][BT][KS];  // Ah, Al, Bh, Bl = 32 KB

    int tid = threadIdx.x;
    int w = tid >> 6;
    int wm = w >> 1, wn = w & 1;
    int lane = tid & 63;
    int lr = lane & 15;
    int k2b = (lane >> 4) << 4;   // byte offset of this lane's 8-bf16 k-group

    int gi0 = bi * BT, gj0 = bj * BT;

    // wave w DMA-stages plane w
    const unsigned short* srcbase = (w & 1) ? Xl : Xh;
    int grow0 = (w < 2) ? gi0 : gj0;
    unsigned short* plane_w = &planes[w][0][0];
    const unsigned short* pAh = &planes[0][0][0];
    const unsigned short* pAl = &planes[1][0][0];
    const unsigned short* pBh = &planes[2][0][0];
    const unsigned short* pBl = &planes[3][0][0];

    int srow = lane >> 2;                    // +c*16
    int sk2  = ((lane & 3) << 4);            // pre-XOR slot

    f32x4 acc[4][4] = {};

    for (int kc = 0; kc < K2; kc += KS) {
        __syncthreads();
#pragma unroll
        for (int c = 0; c < 8; ++c) {
            int row = c * 16 + srow;
            int k2 = sk2 ^ (((row >> 1) & 3) << 4);
            const char* g = (const char*)(srcbase + (size_t)(grow0 + row) * K2 + kc) + k2;
            __builtin_amdgcn_global_load_lds((const void*)g, (void*)((char*)plane_w + c * 1024), 16, 0, 0);
        }
        __syncthreads();

        bf16x8 ahf[4], alf[4], bhf[4], blf[4];
#pragma unroll
        for (int mf = 0; mf < 4; ++mf) {
            int r = wm * 64 + mf * 16 + lr;
            ahf[mf] = frag_ld(pAh, r, k2b);
            alf[mf] = frag_ld(pAl, r, k2b);
        }
#pragma unroll
        for (int nf = 0; nf < 4; ++nf) {
            int r = wn * 64 + nf * 16 + lr;
            bhf[nf] = frag_ld(pBh, r, k2b);
            blf[nf] = frag_ld(pBl, r, k2b);
        }
#pragma unroll
        for (int mf = 0; mf < 4; ++mf)
#pragma unroll
            for (int nf = 0; nf < 4; ++nf) {
                acc[mf][nf] = __builtin_amdgcn_mfma_f32_16x16x32_bf16(ahf[mf], bhf[nf], acc[mf][nf], 0, 0, 0);
                acc[mf][nf] = __builtin_amdgcn_mfma_f32_16x16x32_bf16(ahf[mf], blf[nf], acc[mf][nf], 0, 0, 0);
                acc[mf][nf] = __builtin_amdgcn_mfma_f32_16x16x32_bf16(alf[mf], bhf[nf], acc[mf][nf], 0, 0, 0);
            }
    }

    // epilogue: C/D layout col = lane&15, row = (lane>>4)*4 + reg
    int gi = gi0 + wm * 64, gj = gj0 + wn * 64;
    int rbase = (lane >> 4) << 2;
    float sj[4];
#pragma unroll
    for (int nf = 0; nf < 4; ++nf) sj[nf] = sq[gj + nf * 16 + lr];

    __syncthreads();
    float* red = (float*)planes;   // reuse LDS for reduction scratch

    if (PASS == 1) {
        float mmax = 0.f, mmin = 3e38f;
#pragma unroll
        for (int mf = 0; mf < 4; ++mf)
#pragma unroll
            for (int r = 0; r < 4; ++r) {
                int i = gi + mf * 16 + rbase + r;
                float si = sq[i];
#pragma unroll
                for (int nf = 0; nf < 4; ++nf) {
                    int j = gj + nf * 16 + lr;
                    if (j > i) {
                        float d = si + sj[nf] - 2.0f * acc[mf][nf][r];
                        mmax = fmaxf(mmax, d);
                        mmin = fminf(mmin, d);
                    }
                }
            }
        for (int off = 32; off > 0; off >>= 1) {
            mmax = fmaxf(mmax, __shfl_xor(mmax, off, 64));
            mmin = fminf(mmin, __shfl_xor(mmin, off, 64));
        }
        if (lane == 0) { red[w * 2] = mmax; red[w * 2 + 1] = mmin; }
        __syncthreads();
        if (tid == 0) {
            float M = fmaxf(fmaxf(red[0], red[2]), fmaxf(red[4], red[6]));
            float m = fminf(fminf(red[1], red[3]), fminf(red[5], red[7]));
            atomicMax(tmax, __float_as_uint(M));
            blockmin[L] = m;
        }
    } else {
#pragma unroll
        for (int mf = 0; mf < 4; ++mf)
#pragma unroll
            for (int r = 0; r < 4; ++r) {
                int i = gi + mf * 16 + rbase + r;
                float si = sq[i];
#pragma unroll
                for (int nf = 0; nf < 4; ++nf) {
                    int j = gj + nf * 16 + lr;
                    if (j > i) {
                        float d = si + sj[nf] - 2.0f * acc[mf][nf][r];
                        if (d < t) {
                            unsigned p = atomicAdd(cnt, 1u);
                            if (p < (unsigned)CAP) edges[p] = make_int2(i, j);
                            atomicAdd(&deg[j], 1.0f);
                        }
                    }
                }
            }
    }
}

// ---------------- dinv ----------------
__global__ void dinv_kernel(const float* __restrict__ deg, float* __restrict__ dinv) {
    int i = blockIdx.x * 256 + threadIdx.x;
    if (i < N) dinv[i] = 1.0f / sqrtf(deg[i]);
}

// ---------------- MFMA GEMM: H[M][256] = A[M][Kp]bf16 @ Wt[256][Kp]bf16^T ----------------
// epilogue also writes Z = dinv[row]^2 * H  (fused self-loop aggregation)
__global__ __launch_bounds__(256) void gemm_mfma_kernel(const unsigned short* __restrict__ A,
                                                        const unsigned short* __restrict__ Wt,
                                                        const float* __restrict__ dinv,
                                                        float* __restrict__ H,
                                                        float* __restrict__ Z, int Kp) {
    __shared__ __align__(16) unsigned short Ap[BT][KS];  // 8 KB
    __shared__ __align__(16) unsigned short Bp[BT][KS];  // 8 KB
    int bm = blockIdx.x, bn = blockIdx.y;
    int tid = threadIdx.x;
    int w = tid >> 6;
    int wm = w >> 1, wn = w & 1;
    int lane = tid & 63;
    int lr = lane & 15;
    int k2b = (lane >> 4) << 4;

    int gm0 = bm * BT, gn0 = bn * BT;

    // waves 0,1 stage A (4 calls each); waves 2,3 stage Wt
    const unsigned short* srcbase = (w < 2) ? A + (size_t)gm0 * Kp : Wt + (size_t)gn0 * Kp;
    unsigned short* plane_w = (w < 2) ? &Ap[0][0] : &Bp[0][0];
    int half = (w & 1) * 4096;
    int srow = lane >> 2;
    int sk2 = ((lane & 3) << 4);

    f32x4 acc[4][4] = {};

    for (int kc = 0; kc < Kp; kc += KS) {
        __syncthreads();
#pragma unroll
        for (int c = 0; c < 4; ++c) {
            int off = half + c * 1024;
            int row = (off >> 6) + srow;
            int k2 = sk2 ^ (((row >> 1) & 3) << 4);
            const char* g = (const char*)srcbase + ((size_t)row * Kp + kc) * 2 + k2;
            __builtin_amdgcn_global_load_lds((const void*)g, (void*)((char*)plane_w + off), 16, 0, 0);
        }
        __syncthreads();

        bf16x8 af[4], bf[4];
#pragma unroll
        for (int mf = 0; mf < 4; ++mf) af[mf] = frag_ld(&Ap[0][0], wm * 64 + mf * 16 + lr, k2b);
#pragma unroll
        for (int nf = 0; nf < 4; ++nf) bf[nf] = frag_ld(&Bp[0][0], wn * 64 + nf * 16 + lr, k2b);
#pragma unroll
        for (int mf = 0; mf < 4; ++mf)
#pragma unroll
            for (int nf = 0; nf < 4; ++nf)
                acc[mf][nf] = __builtin_amdgcn_mfma_f32_16x16x32_bf16(af[mf], bf[nf], acc[mf][nf], 0, 0, 0);
    }

    int rbase = (lane >> 4) << 2;
#pragma unroll
    for (int mf = 0; mf < 4; ++mf)
#pragma unroll
        for (int r = 0; r < 4; ++r) {
            int row = gm0 + wm * 64 + mf * 16 + rbase + r;
            float dv = dinv[row];
            float ww = dv * dv;
#pragma unroll
            for (int nf = 0; nf < 4; ++nf) {
                int col = gn0 + wn * 64 + nf * 16 + lr;
                float v = acc[mf][nf][r];
                size_t idx = (size_t)row * NH + col;
                H[idx] = v;
                Z[idx] = ww * v;
            }
        }
}

// ---------------- edge aggregation: Z[j] += dinv_i*dinv_j*H[i] ----------------
__global__ void edgeagg_kernel(const float* __restrict__ H, const float* __restrict__ dinv,
                               const int2* __restrict__ edges, const unsigned* __restrict__ cnt,
                               float* __restrict__ Z) {
    unsigned n = *cnt;
    if (n > (unsigned)CAP) n = CAP;
    int f = threadIdx.x;
    for (unsigned e = blockIdx.x; e < n; e += gridDim.x) {
        int2 ij = edges[e];
        float w = dinv[ij.x] * dinv[ij.y];
        atomicAdd(&Z[(size_t)ij.y * NH + f], w * H[(size_t)ij.x * NH + f]);
    }
}

// ---------------- relu+bias -> x bf16 (next layer input) + column pool ----------------
__global__ void relupool_kernel(const float* __restrict__ Z, const float* __restrict__ b,
                                unsigned short* __restrict__ Xb, float* __restrict__ psum) {
    int f = threadIdx.x;
    int i0 = blockIdx.x * 64;
    float bias = b[f];
    float s = 0.f;
    for (int r = 0; r < 64; r++) {
        size_t idx = (size_t)(i0 + r) * NH + f;
        float v = fmaxf(Z[idx] + bias, 0.f);
        Xb[idx] = f32_to_bf16(v);
        s += v;
    }
    atomicAdd(&psum[f], s);
}

__global__ void finalize_kernel(const float* __restrict__ psum, float* __restrict__ out) {
    int f = threadIdx.x;
    float p = (psum[f] + psum[NH + f] + psum[2 * NH + f]) * (1.0f / (float)N);
    out[f] = p;
    out[NH + f] = p;
}

static inline size_t align_up(size_t x, size_t a) { return (x + a - 1) & ~(a - 1); }

extern "C" void kernel_launch(void* const* d_in, const int* in_sizes, int n_in,
                              void* d_out, int out_size, void* d_ws, size_t ws_size,
                              hipStream_t stream) {
    const float* feature = (const float*)d_in[0];
    const float* W1 = (const float*)d_in[1];
    const float* b1 = (const float*)d_in[2];
    const float* W2 = (const float*)d_in[3];
    const float* b2 = (const float*)d_in[4];
    const float* W3 = (const float*)d_in[5];
    const float* b3 = (const float*)d_in[6];
    float* out = (float*)d_out;

    char* w = (char*)d_ws;
    size_t off = 0;
    float* sq = (float*)(w + off);         off += (size_t)N * 4;
    float* deg = (float*)(w + off);        off += (size_t)N * 4;
    float* dinv = (float*)(w + off);       off += (size_t)N * 4;
    float* psum = (float*)(w + off);       off += 3 * NH * 4;
    unsigned* tmax = (unsigned*)(w + off); off += 4;
    unsigned* cnt = (unsigned*)(w + off);  off += 4;
    off = align_up(off, 256);
    float* blockmin = (float*)(w + off);   off += (size_t)TRI2 * 4;
    off = align_up(off, 256);
    int2* edges = (int2*)(w + off);        off += (size_t)CAP * 8;
    off = align_up(off, 256);
    float* B0 = (float*)(w + off);         off += (size_t)N * NH * 4;   // H
    float* B1 = (float*)(w + off);         off += (size_t)N * NH * 4;   // Z
    off = align_up(off, 256);
    unsigned short* Xh = (unsigned short*)(w + off);  off += (size_t)N * K2 * 2;
    unsigned short* Xl = (unsigned short*)(w + off);  off += (size_t)N * K2 * 2;
    unsigned short* Wt1 = (unsigned short*)(w + off); off += (size_t)NH * K2 * 2;
    unsigned short* Wt2 = (unsigned short*)(w + off); off += (size_t)NH * NH * 2;
    unsigned short* Wt3 = (unsigned short*)(w + off); off += (size_t)NH * NH * 2;
    unsigned short* Xb = (unsigned short*)(w + off);  off += (size_t)N * NH * 2;

    init_kernel<<<N / 256, 256, 0, stream>>>(deg, psum, tmax, cnt);
    prep_kernel<<<N, 256, 0, stream>>>(feature, Xh, Xl, sq);
    wconv_kernel<<<NH, 256, 0, stream>>>(W1, Wt1, F, K2);
    wconv_kernel<<<NH, 256, 0, stream>>>(W2, Wt2, NH, NH);
    wconv_kernel<<<NH, 256, 0, stream>>>(W3, Wt3, NH, NH);
    dist3_kernel<1><<<TRI2, 256, 0, stream>>>(Xh, Xl, sq, tmax, blockmin, cnt, edges, deg);
    dist3_kernel<2><<<TRI2, 256, 0, stream>>>(Xh, Xl, sq, tmax, blockmin, cnt, edges, deg);
    dinv_kernel<<<N / 256, 256, 0, stream>>>(deg, dinv);

    // layer 1 (A-operand: Xh, bf16 hi plane of features, K=512 zero-padded)
    gemm_mfma_kernel<<<dim3(N / BT, NH / BT), 256, 0, stream>>>(Xh, Wt1, dinv, B0, B1, K2);
    edgeagg_kernel<<<64, NH, 0, stream>>>(B0, dinv, edges, cnt, B1);
    relupool_kernel<<<N / 64, NH, 0, stream>>>(B1, b1, Xb, psum);

    // layer 2
    gemm_mfma_kernel<<<dim3(N / BT, NH / BT), 256, 0, stream>>>(Xb, Wt2, dinv, B0, B1, NH);
    edgeagg_kernel<<<64, NH, 0, stream>>>(B0, dinv, edges, cnt, B1);
    relupool_kernel<<<N / 64, NH, 0, stream>>>(B1, b2, Xb, psum + NH);

    // layer 3
    gemm_mfma_kernel<<<dim3(N / BT, NH / BT), 256, 0, stream>>>(Xb, Wt3, dinv, B0, B1, NH);
    edgeagg_kernel<<<64, NH, 0, stream>>>(B0, dinv, edges, cnt, B1);
    relupool_kernel<<<N / 64, NH, 0, stream>>>(B1, b3, Xb, psum + 2 * NH);

    finalize_kernel<<<1, NH, 0, stream>>>(psum, out);
}

// Round 4
// 189.305 us; speedup vs baseline: 5.8710x; 1.2543x over previous
//
#include <hip/hip_runtime.h>

#define N 8192
#define F 500
#define K2 512                      // F padded to MFMA-friendly K
#define NH 256
#define CAP (1 << 17)
#define BT 128                      // dist tile
#define NBT (N / BT)                // 64
#define TRI2 (NBT * (NBT + 1) / 2)  // 2080
#define MARGIN 2.0f                 // |d_hi - d_exact| safety bound for pass-2 block filter

using bf16x8 = __attribute__((ext_vector_type(8))) short;
using f32x4  = __attribute__((ext_vector_type(4))) float;

__device__ __forceinline__ unsigned short f32_to_bf16(float x) {
    unsigned u = __float_as_uint(x);
    u += 0x7fffu + ((u >> 16) & 1u);   // RTNE
    return (unsigned short)(u >> 16);
}
__device__ __forceinline__ float bf16_to_f32(unsigned short h) {
    return __uint_as_float(((unsigned)h) << 16);
}

// KS=32 plane: [128 rows][32 bf16] (64 B rows), 2-bit XOR swizzle (proven r3)
__device__ __forceinline__ bf16x8 frag_ld32(const unsigned short* plane, int r, int k2b) {
    int k2 = k2b ^ (((r >> 1) & 3) << 4);
    return *(const bf16x8*)((const char*)plane + r * 64 + k2);
}
// KS=64 plane: [128 rows][64 bf16] (128 B rows), 3-bit XOR swizzle (slot ^= r&7)
__device__ __forceinline__ bf16x8 frag_ld64(const unsigned short* plane, int r, int k2b) {
    int k2 = k2b ^ ((r & 7) << 4);
    return *(const bf16x8*)((const char*)plane + r * 128 + k2);
}

// ---------------- init ----------------
__global__ void init_kernel(float* deg, float* psum, unsigned* tmax, unsigned* cnt) {
    int i = blockIdx.x * 256 + threadIdx.x;
    if (i < N) deg[i] = 1.0f;
    if (i < 3 * NH) psum[i] = 0.0f;
    if (i == 0) { *tmax = 0u; *cnt = 0u; }
}

// ---------------- split f32 -> bf16 hi/lo (pad K to 512) + sq norms ----------------
__global__ void prep_kernel(const float* __restrict__ X, unsigned short* __restrict__ Xh,
                            unsigned short* __restrict__ Xl, float* __restrict__ sq) {
    __shared__ float red[256];
    int i = blockIdx.x;
    float s = 0.f;
    for (int k = threadIdx.x; k < K2; k += 256) {
        float x = (k < F) ? X[(size_t)i * F + k] : 0.f;
        unsigned short h = f32_to_bf16(x);
        float r = x - bf16_to_f32(h);
        Xh[(size_t)i * K2 + k] = h;
        Xl[(size_t)i * K2 + k] = f32_to_bf16(r);
        s += x * x;
    }
    red[threadIdx.x] = s;
    __syncthreads();
    for (int off = 128; off > 0; off >>= 1) {
        if (threadIdx.x < off) red[threadIdx.x] += red[threadIdx.x + off];
        __syncthreads();
    }
    if (threadIdx.x == 0) sq[i] = red[0];
}

// ---------------- W[K][256] f32 -> Wt[256][Kp] bf16 (transposed, zero-pad) ----------------
__global__ void wconv_kernel(const float* __restrict__ W, unsigned short* __restrict__ Wt,
                             int K, int Kp) {
    int n = blockIdx.x;
    for (int k = threadIdx.x; k < Kp; k += 256) {
        float v = (k < K) ? W[(size_t)k * NH + n] : 0.f;
        Wt[(size_t)n * Kp + k] = f32_to_bf16(v);
    }
}

// ---------------- triangular block decode ----------------
__device__ __forceinline__ void tri_decode(int L, int& bi, int& bj) {
    float a = (float)(2 * NBT + 1);
    bi = (int)((a - sqrtf(a * a - 8.0f * (float)L)) * 0.5f);
    if (bi < 0) bi = 0;
    if (bi > NBT - 1) bi = NBT - 1;
    while (bi > 0 && bi * NBT - bi * (bi - 1) / 2 > L) --bi;
    while (bi < NBT - 1 && (bi + 1) * NBT - (bi + 1) * bi / 2 <= L) ++bi;
    bj = bi + (L - (bi * NBT - bi * (bi - 1) / 2));
}

// ---------------- PASS 1: hi-plane-only distances; global max + per-block min ----------------
__global__ __launch_bounds__(256) void distmax_kernel(const unsigned short* __restrict__ Xh,
                                                      const float* __restrict__ sq,
                                                      unsigned* __restrict__ tmax,
                                                      float* __restrict__ blockmin) {
    int L = (blockIdx.x % 8) * (TRI2 / 8) + blockIdx.x / 8;  // XCD swizzle (2080%8==0)
    int bi, bj;
    tri_decode(L, bi, bj);

    __shared__ __align__(16) unsigned short planes[2][BT][64];  // A,B hi planes, 32 KB

    int tid = threadIdx.x;
    int w = tid >> 6;
    int wm = w >> 1, wn = w & 1;
    int lane = tid & 63;
    int lr = lane & 15;

    int gi0 = bi * BT, gj0 = bj * BT;

    // staging: waves 0,1 -> A plane (row halves), waves 2,3 -> B plane
    const unsigned short* srcb = (w < 2) ? Xh + (size_t)gi0 * K2 : Xh + (size_t)gj0 * K2;
    unsigned short* plane_w = &planes[w >> 1][0][0];
    int rowhalf = (w & 1) * 64;
    int sr = lane >> 3;   // row-in-chunk 0..7
    int ss = lane & 7;    // slot 0..7
    int kb = ((ss ^ sr) << 4);  // pre-swizzled k-byte within 128-B row

    f32x4 acc[4][4] = {};

    for (int kc = 0; kc < K2; kc += 64) {
        __syncthreads();
#pragma unroll
        for (int c = 0; c < 8; ++c) {
            int row = rowhalf + c * 8 + sr;
            const char* g = (const char*)(srcb + (size_t)row * K2 + kc) + kb;
            __builtin_amdgcn_global_load_lds((const void*)g,
                (void*)((char*)plane_w + rowhalf * 128 + c * 1024), 16, 0, 0);
        }
        __syncthreads();
#pragma unroll
        for (int ks = 0; ks < 2; ++ks) {
            int k2b = ks * 64 + ((lane >> 4) << 4);
            bf16x8 af[4], bfr[4];
#pragma unroll
            for (int mf = 0; mf < 4; ++mf) af[mf] = frag_ld64(&planes[0][0][0], wm * 64 + mf * 16 + lr, k2b);
#pragma unroll
            for (int nf = 0; nf < 4; ++nf) bfr[nf] = frag_ld64(&planes[1][0][0], wn * 64 + nf * 16 + lr, k2b);
#pragma unroll
            for (int mf = 0; mf < 4; ++mf)
#pragma unroll
                for (int nf = 0; nf < 4; ++nf)
                    acc[mf][nf] = __builtin_amdgcn_mfma_f32_16x16x32_bf16(af[mf], bfr[nf], acc[mf][nf], 0, 0, 0);
        }
    }

    // epilogue: C/D layout col = lane&15, row = (lane>>4)*4 + reg
    int gi = gi0 + wm * 64, gj = gj0 + wn * 64;
    int rbase = (lane >> 4) << 2;
    float sj[4];
#pragma unroll
    for (int nf = 0; nf < 4; ++nf) sj[nf] = sq[gj + nf * 16 + lr];

    float mmax = 0.f, mmin = 3e38f;
#pragma unroll
    for (int mf = 0; mf < 4; ++mf)
#pragma unroll
        for (int r = 0; r < 4; ++r) {
            int i = gi + mf * 16 + rbase + r;
            float si = sq[i];
#pragma unroll
            for (int nf = 0; nf < 4; ++nf) {
                int j = gj + nf * 16 + lr;
                if (j > i) {
                    float d = si + sj[nf] - 2.0f * acc[mf][nf][r];
                    mmax = fmaxf(mmax, d);
                    mmin = fminf(mmin, d);
                }
            }
        }
    for (int off = 32; off > 0; off >>= 1) {
        mmax = fmaxf(mmax, __shfl_xor(mmax, off, 64));
        mmin = fminf(mmin, __shfl_xor(mmin, off, 64));
    }
    __syncthreads();
    float* red = (float*)planes;
    if (lane == 0) { red[w * 2] = mmax; red[w * 2 + 1] = mmin; }
    __syncthreads();
    if (tid == 0) {
        float M = fmaxf(fmaxf(red[0], red[2]), fmaxf(red[4], red[6]));
        float m = fminf(fminf(red[1], red[3]), fminf(red[5], red[7]));
        atomicMax(tmax, __float_as_uint(M));   // d >= 0, bit-compare valid
        blockmin[L] = m;
    }
}

// ---------------- PASS 2: exact (3-plane) edges, only on candidate blocks ----------------
__global__ __launch_bounds__(256) void edges_kernel(const unsigned short* __restrict__ Xh,
                                                    const unsigned short* __restrict__ Xl,
                                                    const float* __restrict__ sq,
                                                    const unsigned* __restrict__ tmax,
                                                    const float* __restrict__ blockmin,
                                                    unsigned* __restrict__ cnt,
                                                    int2* __restrict__ edges,
                                                    float* __restrict__ deg) {
    int L = (blockIdx.x % 8) * (TRI2 / 8) + blockIdx.x / 8;
    float t = 0.5f * __uint_as_float(*tmax);
    if (!(blockmin[L] < t + MARGIN)) return;   // hi-plane min can't hide an exact-d edge
    int bi, bj;
    tri_decode(L, bi, bj);

    __shared__ __align__(16) unsigned short planes[4][BT][32];  // Ah, Al, Bh, Bl = 32 KB

    int tid = threadIdx.x;
    int w = tid >> 6;
    int wm = w >> 1, wn = w & 1;
    int lane = tid & 63;
    int lr = lane & 15;
    int k2b = (lane >> 4) << 4;

    int gi0 = bi * BT, gj0 = bj * BT;

    const unsigned short* srcbase = (w & 1) ? Xl : Xh;
    int grow0 = (w < 2) ? gi0 : gj0;
    unsigned short* plane_w = &planes[w][0][0];

    int srow = lane >> 2;
    int sk2 = ((lane & 3) << 4);

    f32x4 acc[4][4] = {};

    for (int kc = 0; kc < K2; kc += 32) {
        __syncthreads();
#pragma unroll
        for (int c = 0; c < 8; ++c) {
            int row = c * 16 + srow;
            int k2 = sk2 ^ (((row >> 1) & 3) << 4);
            const char* g = (const char*)(srcbase + (size_t)(grow0 + row) * K2 + kc) + k2;
            __builtin_amdgcn_global_load_lds((const void*)g, (void*)((char*)plane_w + c * 1024), 16, 0, 0);
        }
        __syncthreads();

        bf16x8 ahf[4], alf[4], bhf[4], blf[4];
#pragma unroll
        for (int mf = 0; mf < 4; ++mf) {
            int r = wm * 64 + mf * 16 + lr;
            ahf[mf] = frag_ld32(&planes[0][0][0], r, k2b);
            alf[mf] = frag_ld32(&planes[1][0][0], r, k2b);
        }
#pragma unroll
        for (int nf = 0; nf < 4; ++nf) {
            int r = wn * 64 + nf * 16 + lr;
            bhf[nf] = frag_ld32(&planes[2][0][0], r, k2b);
            blf[nf] = frag_ld32(&planes[3][0][0], r, k2b);
        }
#pragma unroll
        for (int mf = 0; mf < 4; ++mf)
#pragma unroll
            for (int nf = 0; nf < 4; ++nf) {
                acc[mf][nf] = __builtin_amdgcn_mfma_f32_16x16x32_bf16(ahf[mf], bhf[nf], acc[mf][nf], 0, 0, 0);
                acc[mf][nf] = __builtin_amdgcn_mfma_f32_16x16x32_bf16(ahf[mf], blf[nf], acc[mf][nf], 0, 0, 0);
                acc[mf][nf] = __builtin_amdgcn_mfma_f32_16x16x32_bf16(alf[mf], bhf[nf], acc[mf][nf], 0, 0, 0);
            }
    }

    int gi = gi0 + wm * 64, gj = gj0 + wn * 64;
    int rbase = (lane >> 4) << 2;
    float sj[4];
#pragma unroll
    for (int nf = 0; nf < 4; ++nf) sj[nf] = sq[gj + nf * 16 + lr];

#pragma unroll
    for (int mf = 0; mf < 4; ++mf)
#pragma unroll
        for (int r = 0; r < 4; ++r) {
            int i = gi + mf * 16 + rbase + r;
            float si = sq[i];
#pragma unroll
            for (int nf = 0; nf < 4; ++nf) {
                int j = gj + nf * 16 + lr;
                if (j > i) {
                    float d = si + sj[nf] - 2.0f * acc[mf][nf][r];
                    if (d < t) {
                        unsigned p = atomicAdd(cnt, 1u);
                        if (p < (unsigned)CAP) edges[p] = make_int2(i, j);
                        atomicAdd(&deg[j], 1.0f);
                    }
                }
            }
        }
}

// ---------------- dinv ----------------
__global__ void dinv_kernel(const float* __restrict__ deg, float* __restrict__ dinv) {
    int i = blockIdx.x * 256 + threadIdx.x;
    if (i < N) dinv[i] = 1.0f / sqrtf(deg[i]);
}

// ---------------- MFMA GEMM: H[M][256] = A[M][Kp]bf16 @ Wt[256][Kp]bf16^T ----------------
__global__ __launch_bounds__(256) void gemm_mfma_kernel(const unsigned short* __restrict__ A,
                                                        const unsigned short* __restrict__ Wt,
                                                        float* __restrict__ H, int Kp) {
    __shared__ __align__(16) unsigned short Ap[BT][32];
    __shared__ __align__(16) unsigned short Bp[BT][32];
    int bm = blockIdx.x, bn = blockIdx.y;
    int tid = threadIdx.x;
    int w = tid >> 6;
    int wm = w >> 1, wn = w & 1;
    int lane = tid & 63;
    int lr = lane & 15;
    int k2b = (lane >> 4) << 4;

    int gm0 = bm * BT, gn0 = bn * BT;

    const unsigned short* srcbase = (w < 2) ? A + (size_t)gm0 * Kp : Wt + (size_t)gn0 * Kp;
    unsigned short* plane_w = (w < 2) ? &Ap[0][0] : &Bp[0][0];
    int half = (w & 1) * 4096;
    int srow = lane >> 2;
    int sk2 = ((lane & 3) << 4);

    f32x4 acc[4][4] = {};

    for (int kc = 0; kc < Kp; kc += 32) {
        __syncthreads();
#pragma unroll
        for (int c = 0; c < 4; ++c) {
            int off = half + c * 1024;
            int row = (off >> 6) + srow;
            int k2 = sk2 ^ (((row >> 1) & 3) << 4);
            const char* g = (const char*)srcbase + ((size_t)row * Kp + kc) * 2 + k2;
            __builtin_amdgcn_global_load_lds((const void*)g, (void*)((char*)plane_w + off), 16, 0, 0);
        }
        __syncthreads();

        bf16x8 af[4], bfr[4];
#pragma unroll
        for (int mf = 0; mf < 4; ++mf) af[mf] = frag_ld32(&Ap[0][0], wm * 64 + mf * 16 + lr, k2b);
#pragma unroll
        for (int nf = 0; nf < 4; ++nf) bfr[nf] = frag_ld32(&Bp[0][0], wn * 64 + nf * 16 + lr, k2b);
#pragma unroll
        for (int mf = 0; mf < 4; ++mf)
#pragma unroll
            for (int nf = 0; nf < 4; ++nf)
                acc[mf][nf] = __builtin_amdgcn_mfma_f32_16x16x32_bf16(af[mf], bfr[nf], acc[mf][nf], 0, 0, 0);
    }

    int rbase = (lane >> 4) << 2;
#pragma unroll
    for (int mf = 0; mf < 4; ++mf)
#pragma unroll
        for (int r = 0; r < 4; ++r) {
            int row = gm0 + wm * 64 + mf * 16 + rbase + r;
#pragma unroll
            for (int nf = 0; nf < 4; ++nf) {
                int col = gn0 + wn * 64 + nf * 16 + lr;
                H[(size_t)row * NH + col] = acc[mf][nf][r];
            }
        }
}

// ---------------- fused aggregate + bias + relu + bf16 cast + pool ----------------
// block b handles rows [b*64, b*64+64); thread f = feature column
#define ECAP 256
__global__ void relupool2_kernel(const float* __restrict__ H, const float* __restrict__ dinv,
                                 const int2* __restrict__ edges, const unsigned* __restrict__ cnt,
                                 const float* __restrict__ b, unsigned short* __restrict__ Xb,
                                 float* __restrict__ psum) {
    __shared__ int lcnt;
    __shared__ int lsrc[ECAP];
    __shared__ short ltgt[ECAP];
    __shared__ float lw[ECAP];
    int f = threadIdx.x;
    int i0 = blockIdx.x * 64;
    if (f == 0) lcnt = 0;
    __syncthreads();
    unsigned n = *cnt;
    if (n > (unsigned)CAP) n = CAP;
    for (unsigned e = f; e < n; e += 256) {
        int2 ij = edges[e];
        if (ij.y >= i0 && ij.y < i0 + 64) {
            int p = atomicAdd(&lcnt, 1);
            if (p < ECAP) {
                lsrc[p] = ij.x;
                ltgt[p] = (short)(ij.y - i0);
                lw[p] = dinv[ij.x] * dinv[ij.y];
            }
        }
    }
    __syncthreads();
    int m = lcnt < ECAP ? lcnt : ECAP;
    float bias = b[f];
    float s = 0.f;
    for (int r = 0; r < 64; r++) {
        int row = i0 + r;
        float dv = dinv[row];
        float v = dv * dv * H[(size_t)row * NH + f];
        for (int p = 0; p < m; ++p)
            if (ltgt[p] == r) v += lw[p] * H[(size_t)lsrc[p] * NH + f];
        v = fmaxf(v + bias, 0.f);
        Xb[(size_t)row * NH + f] = f32_to_bf16(v);
        s += v;
    }
    atomicAdd(&psum[f], s);
}

__global__ void finalize_kernel(const float* __restrict__ psum, float* __restrict__ out) {
    int f = threadIdx.x;
    float p = (psum[f] + psum[NH + f] + psum[2 * NH + f]) * (1.0f / (float)N);
    out[f] = p;
    out[NH + f] = p;
}

static inline size_t align_up(size_t x, size_t a) { return (x + a - 1) & ~(a - 1); }

extern "C" void kernel_launch(void* const* d_in, const int* in_sizes, int n_in,
                              void* d_out, int out_size, void* d_ws, size_t ws_size,
                              hipStream_t stream) {
    const float* feature = (const float*)d_in[0];
    const float* W1 = (const float*)d_in[1];
    const float* b1 = (const float*)d_in[2];
    const float* W2 = (const float*)d_in[3];
    const float* b2 = (const float*)d_in[4];
    const float* W3 = (const float*)d_in[5];
    const float* b3 = (const float*)d_in[6];
    float* out = (float*)d_out;

    char* w = (char*)d_ws;
    size_t off = 0;
    float* sq = (float*)(w + off);         off += (size_t)N * 4;
    float* deg = (float*)(w + off);        off += (size_t)N * 4;
    float* dinv = (float*)(w + off);       off += (size_t)N * 4;
    float* psum = (float*)(w + off);       off += 3 * NH * 4;
    unsigned* tmax = (unsigned*)(w + off); off += 4;
    unsigned* cnt = (unsigned*)(w + off);  off += 4;
    off = align_up(off, 256);
    float* blockmin = (float*)(w + off);   off += (size_t)TRI2 * 4;
    off = align_up(off, 256);
    int2* edges = (int2*)(w + off);        off += (size_t)CAP * 8;
    off = align_up(off, 256);
    float* H = (float*)(w + off);          off += (size_t)N * NH * 4;
    off = align_up(off, 256);
    unsigned short* Xh = (unsigned short*)(w + off);  off += (size_t)N * K2 * 2;
    unsigned short* Xl = (unsigned short*)(w + off);  off += (size_t)N * K2 * 2;
    unsigned short* Wt1 = (unsigned short*)(w + off); off += (size_t)NH * K2 * 2;
    unsigned short* Wt2 = (unsigned short*)(w + off); off += (size_t)NH * NH * 2;
    unsigned short* Wt3 = (unsigned short*)(w + off); off += (size_t)NH * NH * 2;
    unsigned short* Xb = (unsigned short*)(w + off);  off += (size_t)N * NH * 2;

    init_kernel<<<N / 256, 256, 0, stream>>>(deg, psum, tmax, cnt);
    prep_kernel<<<N, 256, 0, stream>>>(feature, Xh, Xl, sq);
    wconv_kernel<<<NH, 256, 0, stream>>>(W1, Wt1, F, K2);
    wconv_kernel<<<NH, 256, 0, stream>>>(W2, Wt2, NH, NH);
    wconv_kernel<<<NH, 256, 0, stream>>>(W3, Wt3, NH, NH);
    distmax_kernel<<<TRI2, 256, 0, stream>>>(Xh, sq, tmax, blockmin);
    edges_kernel<<<TRI2, 256, 0, stream>>>(Xh, Xl, sq, tmax, blockmin, cnt, edges, deg);
    dinv_kernel<<<N / 256, 256, 0, stream>>>(deg, dinv);

    // layer 1
    gemm_mfma_kernel<<<dim3(N / BT, NH / BT), 256, 0, stream>>>(Xh, Wt1, H, K2);
    relupool2_kernel<<<N / 64, NH, 0, stream>>>(H, dinv, edges, cnt, b1, Xb, psum);

    // layer 2
    gemm_mfma_kernel<<<dim3(N / BT, NH / BT), 256, 0, stream>>>(Xb, Wt2, H, NH);
    relupool2_kernel<<<N / 64, NH, 0, stream>>>(H, dinv, edges, cnt, b2, Xb, psum + NH);

    // layer 3
    gemm_mfma_kernel<<<dim3(N / BT, NH / BT), 256, 0, stream>>>(Xb, Wt3, H, NH);
    relupool2_kernel<<<N / 64, NH, 0, stream>>>(H, dinv, edges, cnt, b3, Xb, psum + 2 * NH);

    finalize_kernel<<<1, NH, 0, stream>>>(psum, out);
}

// Round 5
// 183.570 us; speedup vs baseline: 6.0544x; 1.0312x over previous
//
#include <hip/hip_runtime.h>

#define N 8192
#define F 500
#define K2 512                      // F padded to MFMA-friendly K
#define NH 256
#define CAP (1 << 17)
#define BT 128                      // dist tile
#define NBT (N / BT)                // 64
#define TRI2 (NBT * (NBT + 1) / 2)  // 2080
#define MARGIN 2.0f                 // |d_hi - d_exact| safety bound for pass-2 block filter

using bf16x8 = __attribute__((ext_vector_type(8))) short;
using f32x4  = __attribute__((ext_vector_type(4))) float;

__device__ __forceinline__ unsigned short f32_to_bf16(float x) {
    unsigned u = __float_as_uint(x);
    u += 0x7fffu + ((u >> 16) & 1u);   // RTNE
    return (unsigned short)(u >> 16);
}
__device__ __forceinline__ float bf16_to_f32(unsigned short h) {
    return __uint_as_float(((unsigned)h) << 16);
}

// KS=32 plane: [128 rows][32 bf16] (64 B rows), 2-bit XOR swizzle
__device__ __forceinline__ bf16x8 frag_ld32(const unsigned short* plane, int r, int k2b) {
    int k2 = k2b ^ (((r >> 1) & 3) << 4);
    return *(const bf16x8*)((const char*)plane + r * 64 + k2);
}
// KS=64 plane: [128 rows][64 bf16] (128 B rows), 3-bit XOR swizzle (slot ^= r&7)
__device__ __forceinline__ bf16x8 frag_ld64(const unsigned short* plane, int r, int k2b) {
    int k2 = k2b ^ ((r & 7) << 4);
    return *(const bf16x8*)((const char*)plane + r * 128 + k2);
}

// ---------------- prep: init + split f32 -> bf16 hi/lo + sq norms ----------------
__global__ void prep_kernel(const float* __restrict__ X, unsigned short* __restrict__ Xh,
                            unsigned short* __restrict__ Xl, float* __restrict__ sq,
                            float* __restrict__ deg, float* __restrict__ psum,
                            unsigned* __restrict__ tmax, unsigned* __restrict__ cnt) {
    __shared__ float red[256];
    int i = blockIdx.x;
    if (threadIdx.x == 0) deg[i] = 1.0f;     // self-loop
    if (i == 0) {
        for (int k = threadIdx.x; k < 3 * NH; k += 256) psum[k] = 0.f;
        if (threadIdx.x == 0) { *tmax = 0u; *cnt = 0u; }
    }
    float s = 0.f;
    for (int k = threadIdx.x; k < K2; k += 256) {
        float x = (k < F) ? X[(size_t)i * F + k] : 0.f;
        unsigned short h = f32_to_bf16(x);
        float r = x - bf16_to_f32(h);
        Xh[(size_t)i * K2 + k] = h;
        Xl[(size_t)i * K2 + k] = f32_to_bf16(r);
        s += x * x;
    }
    red[threadIdx.x] = s;
    __syncthreads();
    for (int off = 128; off > 0; off >>= 1) {
        if (threadIdx.x < off) red[threadIdx.x] += red[threadIdx.x + off];
        __syncthreads();
    }
    if (threadIdx.x == 0) sq[i] = red[0];
}

// ---------------- all three W[K][256] f32 -> Wt[256][Kp] bf16 (transposed, pad) ----------------
__global__ void wconv3_kernel(const float* __restrict__ W1, const float* __restrict__ W2,
                              const float* __restrict__ W3, unsigned short* __restrict__ Wt1,
                              unsigned short* __restrict__ Wt2, unsigned short* __restrict__ Wt3) {
    int n = blockIdx.x, which = blockIdx.y;
    const float* W = which == 0 ? W1 : (which == 1 ? W2 : W3);
    unsigned short* Wt = which == 0 ? Wt1 : (which == 1 ? Wt2 : Wt3);
    int K = which == 0 ? F : NH;
    int Kp = which == 0 ? K2 : NH;
    for (int k = threadIdx.x; k < Kp; k += 256) {
        float v = (k < K) ? W[(size_t)k * NH + n] : 0.f;
        Wt[(size_t)n * Kp + k] = f32_to_bf16(v);
    }
}

// ---------------- triangular block decode ----------------
__device__ __forceinline__ void tri_decode(int L, int& bi, int& bj) {
    float a = (float)(2 * NBT + 1);
    bi = (int)((a - sqrtf(a * a - 8.0f * (float)L)) * 0.5f);
    if (bi < 0) bi = 0;
    if (bi > NBT - 1) bi = NBT - 1;
    while (bi > 0 && bi * NBT - bi * (bi - 1) / 2 > L) --bi;
    while (bi < NBT - 1 && (bi + 1) * NBT - (bi + 1) * bi / 2 <= L) ++bi;
    bj = bi + (L - (bi * NBT - bi * (bi - 1) / 2));
}

// ---------------- PASS 1: hi-plane distances; global max + per-block min (dbuf) ----------------
__global__ __launch_bounds__(256) void distmax_kernel(const unsigned short* __restrict__ Xh,
                                                      const float* __restrict__ sq,
                                                      unsigned* __restrict__ tmax,
                                                      float* __restrict__ blockmin) {
    int L = (blockIdx.x % 8) * (TRI2 / 8) + blockIdx.x / 8;  // XCD swizzle (2080%8==0)
    int bi, bj;
    tri_decode(L, bi, bj);

    __shared__ __align__(16) unsigned short P[2][2][BT][64];  // dbuf x {A,B} = 64 KB

    int tid = threadIdx.x;
    int w = tid >> 6;
    int wm = w >> 1, wn = w & 1;
    int lane = tid & 63;
    int lr = lane & 15;

    int gi0 = bi * BT, gj0 = bj * BT;

    // staging: waves 0,1 -> A plane (row halves), waves 2,3 -> B plane
    const unsigned short* srcb = (w < 2) ? Xh + (size_t)gi0 * K2 : Xh + (size_t)gj0 * K2;
    int pidx = w >> 1;
    int rowhalf = (w & 1) * 64;
    int sr = lane >> 3;          // row-in-chunk 0..7
    int ss = lane & 7;           // slot 0..7
    int kb = ((ss ^ sr) << 4);   // pre-swizzled k-byte within 128-B row

    auto STAGE = [&](int buf, int kc) {
        char* dst = (char*)&P[buf][pidx][0][0] + rowhalf * 128;
#pragma unroll
        for (int c = 0; c < 8; ++c) {
            int row = rowhalf + c * 8 + sr;
            const char* g = (const char*)(srcb + (size_t)row * K2 + kc) + kb;
            __builtin_amdgcn_global_load_lds((const void*)g, (void*)(dst + c * 1024), 16, 0, 0);
        }
    };

    f32x4 acc[4][4] = {};

    STAGE(0, 0);
    __syncthreads();
    int cur = 0;
#pragma unroll
    for (int t = 0; t < K2 / 64; ++t) {
        if (t < K2 / 64 - 1) STAGE(cur ^ 1, (t + 1) * 64);
        const unsigned short* pA = &P[cur][0][0][0];
        const unsigned short* pB = &P[cur][1][0][0];
#pragma unroll
        for (int ks = 0; ks < 2; ++ks) {
            int k2b = ks * 64 + ((lane >> 4) << 4);
            bf16x8 af[4], bfr[4];
#pragma unroll
            for (int mf = 0; mf < 4; ++mf) af[mf] = frag_ld64(pA, wm * 64 + mf * 16 + lr, k2b);
#pragma unroll
            for (int nf = 0; nf < 4; ++nf) bfr[nf] = frag_ld64(pB, wn * 64 + nf * 16 + lr, k2b);
#pragma unroll
            for (int mf = 0; mf < 4; ++mf)
#pragma unroll
                for (int nf = 0; nf < 4; ++nf)
                    acc[mf][nf] = __builtin_amdgcn_mfma_f32_16x16x32_bf16(af[mf], bfr[nf], acc[mf][nf], 0, 0, 0);
        }
        __syncthreads();   // drains vmcnt (prefetch) + lgkm; one barrier per K-step
        cur ^= 1;
    }

    // epilogue: C/D layout col = lane&15, row = (lane>>4)*4 + reg
    int gi = gi0 + wm * 64, gj = gj0 + wn * 64;
    int rbase = (lane >> 4) << 2;
    float sj[4];
#pragma unroll
    for (int nf = 0; nf < 4; ++nf) sj[nf] = sq[gj + nf * 16 + lr];

    float mmax = 0.f, mmin = 3e38f;
#pragma unroll
    for (int mf = 0; mf < 4; ++mf)
#pragma unroll
        for (int r = 0; r < 4; ++r) {
            int i = gi + mf * 16 + rbase + r;
            float si = sq[i];
#pragma unroll
            for (int nf = 0; nf < 4; ++nf) {
                int j = gj + nf * 16 + lr;
                if (j > i) {
                    float d = si + sj[nf] - 2.0f * acc[mf][nf][r];
                    mmax = fmaxf(mmax, d);
                    mmin = fminf(mmin, d);
                }
            }
        }
    for (int off = 32; off > 0; off >>= 1) {
        mmax = fmaxf(mmax, __shfl_xor(mmax, off, 64));
        mmin = fminf(mmin, __shfl_xor(mmin, off, 64));
    }
    __syncthreads();
    float* red = (float*)P;
    if (lane == 0) { red[w * 2] = mmax; red[w * 2 + 1] = mmin; }
    __syncthreads();
    if (tid == 0) {
        float M = fmaxf(fmaxf(red[0], red[2]), fmaxf(red[4], red[6]));
        float m = fminf(fminf(red[1], red[3]), fminf(red[5], red[7]));
        atomicMax(tmax, __float_as_uint(M));   // d >= 0, bit-compare valid
        blockmin[L] = m;
    }
}

// ---------------- PASS 2: exact (3-plane) edges, only on candidate blocks ----------------
__global__ __launch_bounds__(256) void edges_kernel(const unsigned short* __restrict__ Xh,
                                                    const unsigned short* __restrict__ Xl,
                                                    const float* __restrict__ sq,
                                                    const unsigned* __restrict__ tmax,
                                                    const float* __restrict__ blockmin,
                                                    unsigned* __restrict__ cnt,
                                                    int2* __restrict__ edges,
                                                    float* __restrict__ deg) {
    int L = (blockIdx.x % 8) * (TRI2 / 8) + blockIdx.x / 8;
    float t = 0.5f * __uint_as_float(*tmax);
    if (!(blockmin[L] < t + MARGIN)) return;   // hi-plane min can't hide an exact-d edge
    int bi, bj;
    tri_decode(L, bi, bj);

    __shared__ __align__(16) unsigned short planes[4][BT][32];  // Ah, Al, Bh, Bl = 32 KB

    int tid = threadIdx.x;
    int w = tid >> 6;
    int wm = w >> 1, wn = w & 1;
    int lane = tid & 63;
    int lr = lane & 15;
    int k2b = (lane >> 4) << 4;

    int gi0 = bi * BT, gj0 = bj * BT;

    const unsigned short* srcbase = (w & 1) ? Xl : Xh;
    int grow0 = (w < 2) ? gi0 : gj0;
    unsigned short* plane_w = &planes[w][0][0];

    int srow = lane >> 2;
    int sk2 = ((lane & 3) << 4);

    f32x4 acc[4][4] = {};

    for (int kc = 0; kc < K2; kc += 32) {
        __syncthreads();
#pragma unroll
        for (int c = 0; c < 8; ++c) {
            int row = c * 16 + srow;
            int k2 = sk2 ^ (((row >> 1) & 3) << 4);
            const char* g = (const char*)(srcbase + (size_t)(grow0 + row) * K2 + kc) + k2;
            __builtin_amdgcn_global_load_lds((const void*)g, (void*)((char*)plane_w + c * 1024), 16, 0, 0);
        }
        __syncthreads();

        bf16x8 ahf[4], alf[4], bhf[4], blf[4];
#pragma unroll
        for (int mf = 0; mf < 4; ++mf) {
            int r = wm * 64 + mf * 16 + lr;
            ahf[mf] = frag_ld32(&planes[0][0][0], r, k2b);
            alf[mf] = frag_ld32(&planes[1][0][0], r, k2b);
        }
#pragma unroll
        for (int nf = 0; nf < 4; ++nf) {
            int r = wn * 64 + nf * 16 + lr;
            bhf[nf] = frag_ld32(&planes[2][0][0], r, k2b);
            blf[nf] = frag_ld32(&planes[3][0][0], r, k2b);
        }
#pragma unroll
        for (int mf = 0; mf < 4; ++mf)
#pragma unroll
            for (int nf = 0; nf < 4; ++nf) {
                acc[mf][nf] = __builtin_amdgcn_mfma_f32_16x16x32_bf16(ahf[mf], bhf[nf], acc[mf][nf], 0, 0, 0);
                acc[mf][nf] = __builtin_amdgcn_mfma_f32_16x16x32_bf16(ahf[mf], blf[nf], acc[mf][nf], 0, 0, 0);
                acc[mf][nf] = __builtin_amdgcn_mfma_f32_16x16x32_bf16(alf[mf], bhf[nf], acc[mf][nf], 0, 0, 0);
            }
    }

    int gi = gi0 + wm * 64, gj = gj0 + wn * 64;
    int rbase = (lane >> 4) << 2;
    float sj[4];
#pragma unroll
    for (int nf = 0; nf < 4; ++nf) sj[nf] = sq[gj + nf * 16 + lr];

#pragma unroll
    for (int mf = 0; mf < 4; ++mf)
#pragma unroll
        for (int r = 0; r < 4; ++r) {
            int i = gi + mf * 16 + rbase + r;
            float si = sq[i];
#pragma unroll
            for (int nf = 0; nf < 4; ++nf) {
                int j = gj + nf * 16 + lr;
                if (j > i) {
                    float d = si + sj[nf] - 2.0f * acc[mf][nf][r];
                    if (d < t) {
                        unsigned p = atomicAdd(cnt, 1u);
                        if (p < (unsigned)CAP) edges[p] = make_int2(i, j);
                        atomicAdd(&deg[j], 1.0f);
                    }
                }
            }
        }
}

// ---------------- MFMA GEMM (dbuf): H[M][256] = A[M][Kp]bf16 @ Wt[256][Kp]bf16^T ----------------
__global__ __launch_bounds__(256) void gemm_mfma_kernel(const unsigned short* __restrict__ A,
                                                        const unsigned short* __restrict__ Wt,
                                                        float* __restrict__ H, int Kp) {
    __shared__ __align__(16) unsigned short P[2][2][BT][32];  // dbuf x {A,B} = 32 KB
    int bm = blockIdx.x, bn = blockIdx.y;
    int tid = threadIdx.x;
    int w = tid >> 6;
    int wm = w >> 1, wn = w & 1;
    int lane = tid & 63;
    int lr = lane & 15;
    int k2b = (lane >> 4) << 4;

    int gm0 = bm * BT, gn0 = bn * BT;

    const unsigned short* srcbase = (w < 2) ? A + (size_t)gm0 * Kp : Wt + (size_t)gn0 * Kp;
    int pidx = w < 2 ? 0 : 1;
    int half = (w & 1) * 4096;
    int srow = lane >> 2;
    int sk2 = ((lane & 3) << 4);

    auto STAGE = [&](int buf, int kc) {
        char* dst = (char*)&P[buf][pidx][0][0];
#pragma unroll
        for (int c = 0; c < 4; ++c) {
            int off = half + c * 1024;
            int row = (off >> 6) + srow;
            int k2 = sk2 ^ (((row >> 1) & 3) << 4);
            const char* g = (const char*)srcbase + ((size_t)row * Kp + kc) * 2 + k2;
            __builtin_amdgcn_global_load_lds((const void*)g, (void*)(dst + off), 16, 0, 0);
        }
    };

    f32x4 acc[4][4] = {};

    STAGE(0, 0);
    __syncthreads();
    int cur = 0;
    int nt = Kp / 32;
    for (int t = 0; t < nt; ++t) {
        if (t < nt - 1) STAGE(cur ^ 1, (t + 1) * 32);
        const unsigned short* pA = &P[cur][0][0][0];
        const unsigned short* pB = &P[cur][1][0][0];
        bf16x8 af[4], bfr[4];
#pragma unroll
        for (int mf = 0; mf < 4; ++mf) af[mf] = frag_ld32(pA, wm * 64 + mf * 16 + lr, k2b);
#pragma unroll
        for (int nf = 0; nf < 4; ++nf) bfr[nf] = frag_ld32(pB, wn * 64 + nf * 16 + lr, k2b);
#pragma unroll
        for (int mf = 0; mf < 4; ++mf)
#pragma unroll
            for (int nf = 0; nf < 4; ++nf)
                acc[mf][nf] = __builtin_amdgcn_mfma_f32_16x16x32_bf16(af[mf], bfr[nf], acc[mf][nf], 0, 0, 0);
        __syncthreads();
        cur ^= 1;
    }

    int rbase = (lane >> 4) << 2;
#pragma unroll
    for (int mf = 0; mf < 4; ++mf)
#pragma unroll
        for (int r = 0; r < 4; ++r) {
            int row = gm0 + wm * 64 + mf * 16 + rbase + r;
#pragma unroll
            for (int nf = 0; nf < 4; ++nf) {
                int col = gn0 + wn * 64 + nf * 16 + lr;
                H[(size_t)row * NH + col] = acc[mf][nf][r];
            }
        }
}

// ---------------- fused aggregate + bias + relu + bf16 cast + pool ----------------
#define ECAP 256
__global__ void relupool2_kernel(const float* __restrict__ H, const float* __restrict__ deg,
                                 const int2* __restrict__ edges, const unsigned* __restrict__ cnt,
                                 const float* __restrict__ b, unsigned short* __restrict__ Xb,
                                 float* __restrict__ psum) {
    __shared__ int lcnt;
    __shared__ int lsrc[ECAP];
    __shared__ short ltgt[ECAP];
    __shared__ float lw[ECAP];
    int f = threadIdx.x;
    int i0 = blockIdx.x * 64;
    if (f == 0) lcnt = 0;
    __syncthreads();
    unsigned n = *cnt;
    if (n > (unsigned)CAP) n = CAP;
    for (unsigned e = f; e < n; e += 256) {
        int2 ij = edges[e];
        if (ij.y >= i0 && ij.y < i0 + 64) {
            int p = atomicAdd(&lcnt, 1);
            if (p < ECAP) {
                lsrc[p] = ij.x;
                ltgt[p] = (short)(ij.y - i0);
                lw[p] = (1.0f / sqrtf(deg[ij.x])) * (1.0f / sqrtf(deg[ij.y]));
            }
        }
    }
    __syncthreads();
    int m = lcnt < ECAP ? lcnt : ECAP;
    float bias = b[f];
    float s = 0.f;
    for (int r = 0; r < 64; r++) {
        int row = i0 + r;
        float v = H[(size_t)row * NH + f] / deg[row];   // dinv^2 = 1/deg
        for (int p = 0; p < m; ++p)
            if (ltgt[p] == r) v += lw[p] * H[(size_t)lsrc[p] * NH + f];
        v = fmaxf(v + bias, 0.f);
        Xb[(size_t)row * NH + f] = f32_to_bf16(v);
        s += v;
    }
    atomicAdd(&psum[f], s);
}

__global__ void finalize_kernel(const float* __restrict__ psum, float* __restrict__ out) {
    int f = threadIdx.x;
    float p = (psum[f] + psum[NH + f] + psum[2 * NH + f]) * (1.0f / (float)N);
    out[f] = p;
    out[NH + f] = p;
}

static inline size_t align_up(size_t x, size_t a) { return (x + a - 1) & ~(a - 1); }

extern "C" void kernel_launch(void* const* d_in, const int* in_sizes, int n_in,
                              void* d_out, int out_size, void* d_ws, size_t ws_size,
                              hipStream_t stream) {
    const float* feature = (const float*)d_in[0];
    const float* W1 = (const float*)d_in[1];
    const float* b1 = (const float*)d_in[2];
    const float* W2 = (const float*)d_in[3];
    const float* b2 = (const float*)d_in[4];
    const float* W3 = (const float*)d_in[5];
    const float* b3 = (const float*)d_in[6];
    float* out = (float*)d_out;

    char* w = (char*)d_ws;
    size_t off = 0;
    float* sq = (float*)(w + off);         off += (size_t)N * 4;
    float* deg = (float*)(w + off);        off += (size_t)N * 4;
    float* psum = (float*)(w + off);       off += 3 * NH * 4;
    unsigned* tmax = (unsigned*)(w + off); off += 4;
    unsigned* cnt = (unsigned*)(w + off);  off += 4;
    off = align_up(off, 256);
    float* blockmin = (float*)(w + off);   off += (size_t)TRI2 * 4;
    off = align_up(off, 256);
    int2* edges = (int2*)(w + off);        off += (size_t)CAP * 8;
    off = align_up(off, 256);
    float* H = (float*)(w + off);          off += (size_t)N * NH * 4;
    off = align_up(off, 256);
    unsigned short* Xh = (unsigned short*)(w + off);  off += (size_t)N * K2 * 2;
    unsigned short* Xl = (unsigned short*)(w + off);  off += (size_t)N * K2 * 2;
    unsigned short* Wt1 = (unsigned short*)(w + off); off += (size_t)NH * K2 * 2;
    unsigned short* Wt2 = (unsigned short*)(w + off); off += (size_t)NH * NH * 2;
    unsigned short* Wt3 = (unsigned short*)(w + off); off += (size_t)NH * NH * 2;
    unsigned short* Xb = (unsigned short*)(w + off);  off += (size_t)N * NH * 2;

    prep_kernel<<<N, 256, 0, stream>>>(feature, Xh, Xl, sq, deg, psum, tmax, cnt);
    wconv3_kernel<<<dim3(NH, 3), 256, 0, stream>>>(W1, W2, W3, Wt1, Wt2, Wt3);
    distmax_kernel<<<TRI2, 256, 0, stream>>>(Xh, sq, tmax, blockmin);
    edges_kernel<<<TRI2, 256, 0, stream>>>(Xh, Xl, sq, tmax, blockmin, cnt, edges, deg);

    // layer 1
    gemm_mfma_kernel<<<dim3(N / BT, NH / BT), 256, 0, stream>>>(Xh, Wt1, H, K2);
    relupool2_kernel<<<N / 64, NH, 0, stream>>>(H, deg, edges, cnt, b1, Xb, psum);

    // layer 2
    gemm_mfma_kernel<<<dim3(N / BT, NH / BT), 256, 0, stream>>>(Xb, Wt2, H, NH);
    relupool2_kernel<<<N / 64, NH, 0, stream>>>(H, deg, edges, cnt, b2, Xb, psum + NH);

    // layer 3
    gemm_mfma_kernel<<<dim3(N / BT, NH / BT), 256, 0, stream>>>(Xb, Wt3, H, NH);
    relupool2_kernel<<<N / 64, NH, 0, stream>>>(H, deg, edges, cnt, b3, Xb, psum + 2 * NH);

    finalize_kernel<<<1, NH, 0, stream>>>(psum, out);
}

// Round 6
// 162.099 us; speedup vs baseline: 6.8564x; 1.1325x over previous
//
#include <hip/hip_runtime.h>

#define N 8192
#define F 500
#define K2 512                        // F padded to MFMA-friendly K
#define NH 256
#define CAP (1 << 17)
#define BT 128                        // pass-2 tile
#define NBT (N / BT)                  // 64
#define TRI2 (NBT * (NBT + 1) / 2)    // 2080
#define BT2 256                       // pass-1 tile
#define NBT2 (N / BT2)                // 32
#define TRI256 (NBT2 * (NBT2 + 1) / 2)  // 528
#define MARGIN 2.0f                   // |d_hi - d_exact| safety bound

using bf16x8 = __attribute__((ext_vector_type(8))) short;
using f32x4  = __attribute__((ext_vector_type(4))) float;

__device__ __forceinline__ unsigned short f32_to_bf16(float x) {
    unsigned u = __float_as_uint(x);
    u += 0x7fffu + ((u >> 16) & 1u);   // RTNE
    return (unsigned short)(u >> 16);
}
__device__ __forceinline__ float bf16_to_f32(unsigned short h) {
    return __uint_as_float(((unsigned)h) << 16);
}

// KS=32 plane: [rows][32 bf16] (64 B rows), 2-bit XOR swizzle
__device__ __forceinline__ bf16x8 frag_ld32(const unsigned short* plane, int r, int k2b) {
    int k2 = k2b ^ (((r >> 1) & 3) << 4);
    return *(const bf16x8*)((const char*)plane + r * 64 + k2);
}
// KS=64 plane: [rows][64 bf16] (128 B rows), 3-bit XOR swizzle (slot ^= r&7)
__device__ __forceinline__ bf16x8 frag_ld64(const unsigned short* plane, int r, int k2b) {
    int k2 = k2b ^ ((r & 7) << 4);
    return *(const bf16x8*)((const char*)plane + r * 128 + k2);
}

// ---------------- prep: init + split f32 -> bf16 hi/lo + sq norms ----------------
__global__ void prep_kernel(const float* __restrict__ X, unsigned short* __restrict__ Xh,
                            unsigned short* __restrict__ Xl, float* __restrict__ sq,
                            float* __restrict__ deg, float* __restrict__ psum,
                            unsigned* __restrict__ tmax, unsigned* __restrict__ cnt) {
    __shared__ float red[256];
    int i = blockIdx.x;
    if (threadIdx.x == 0) deg[i] = 1.0f;     // self-loop
    if (i == 0) {
        for (int k = threadIdx.x; k < 3 * NH; k += 256) psum[k] = 0.f;
        if (threadIdx.x == 0) { *tmax = 0u; *cnt = 0u; }
    }
    float s = 0.f;
    for (int k = threadIdx.x; k < K2; k += 256) {
        float x = (k < F) ? X[(size_t)i * F + k] : 0.f;
        unsigned short h = f32_to_bf16(x);
        float r = x - bf16_to_f32(h);
        Xh[(size_t)i * K2 + k] = h;
        Xl[(size_t)i * K2 + k] = f32_to_bf16(r);
        s += x * x;
    }
    red[threadIdx.x] = s;
    __syncthreads();
    for (int off = 128; off > 0; off >>= 1) {
        if (threadIdx.x < off) red[threadIdx.x] += red[threadIdx.x + off];
        __syncthreads();
    }
    if (threadIdx.x == 0) sq[i] = red[0];
}

// ---------------- all three W[K][256] f32 -> Wt[256][Kp] bf16 ----------------
__global__ void wconv3_kernel(const float* __restrict__ W1, const float* __restrict__ W2,
                              const float* __restrict__ W3, unsigned short* __restrict__ Wt1,
                              unsigned short* __restrict__ Wt2, unsigned short* __restrict__ Wt3) {
    int n = blockIdx.x, which = blockIdx.y;
    const float* W = which == 0 ? W1 : (which == 1 ? W2 : W3);
    unsigned short* Wt = which == 0 ? Wt1 : (which == 1 ? Wt2 : Wt3);
    int K = which == 0 ? F : NH;
    int Kp = which == 0 ? K2 : NH;
    for (int k = threadIdx.x; k < Kp; k += 256) {
        float v = (k < K) ? W[(size_t)k * NH + n] : 0.f;
        Wt[(size_t)n * Kp + k] = f32_to_bf16(v);
    }
}

// ---------------- triangular block decode (nb x nb upper-tri) ----------------
__device__ __forceinline__ void tri_decode(int L, int nb, int& bi, int& bj) {
    float a = (float)(2 * nb + 1);
    bi = (int)((a - sqrtf(a * a - 8.0f * (float)L)) * 0.5f);
    if (bi < 0) bi = 0;
    if (bi > nb - 1) bi = nb - 1;
    while (bi > 0 && bi * nb - bi * (bi - 1) / 2 > L) --bi;
    while (bi < nb - 1 && (bi + 1) * nb - (bi + 1) * bi / 2 <= L) ++bi;
    bj = bi + (L - (bi * nb - bi * (bi - 1) / 2));
}

// ---------------- PASS 1: 256^2 tile, hi-plane distances; max + per-block min ----------------
__global__ __launch_bounds__(512, 2) void distmax_kernel(const unsigned short* __restrict__ Xh,
                                                         const float* __restrict__ sq,
                                                         unsigned* __restrict__ tmax,
                                                         float* __restrict__ blockmin) {
    int L = (blockIdx.x % 8) * (TRI256 / 8) + blockIdx.x / 8;  // XCD swizzle (528%8==0)
    int bi, bj;
    tri_decode(L, NBT2, bi, bj);

    __shared__ __align__(16) unsigned short P[2][2][BT2][64];  // dbuf x {A,B} = 128 KB

    int tid = threadIdx.x;
    int w = tid >> 6;                 // 8 waves: 2 (M) x 4 (N)
    int wm = w >> 2, wn = w & 3;
    int lane = tid & 63;
    int lr = lane & 15;

    int gi0 = bi * BT2, gj0 = bj * BT2;

    // staging: waves 0-3 stage A plane (64-row quarters), waves 4-7 stage B plane
    const unsigned short* srcb = (w < 4) ? Xh + (size_t)gi0 * K2 : Xh + (size_t)gj0 * K2;
    int pidx = w >> 2;
    int rowbase = (w & 3) * 64;
    int sr = lane >> 3;          // row-in-chunk 0..7
    int ss = lane & 7;           // slot 0..7
    int kb = ((ss ^ sr) << 4);   // pre-swizzled k-byte within 128-B row

    auto STAGE = [&](int buf, int kc) {
        char* dst = (char*)&P[buf][pidx][0][0] + rowbase * 128;
#pragma unroll
        for (int c = 0; c < 8; ++c) {
            int row = rowbase + c * 8 + sr;
            const char* g = (const char*)(srcb + (size_t)row * K2 + kc) + kb;
            __builtin_amdgcn_global_load_lds((const void*)g, (void*)(dst + c * 1024), 16, 0, 0);
        }
    };

    f32x4 acc[8][4] = {};

    STAGE(0, 0);
    __syncthreads();
    int cur = 0;
#pragma unroll
    for (int t = 0; t < K2 / 64; ++t) {
        if (t < K2 / 64 - 1) STAGE(cur ^ 1, (t + 1) * 64);
        const unsigned short* pA = &P[cur][0][0][0];
        const unsigned short* pB = &P[cur][1][0][0];
#pragma unroll
        for (int ks = 0; ks < 2; ++ks) {
            int k2b = ks * 64 + ((lane >> 4) << 4);
            bf16x8 af[8], bfr[4];
#pragma unroll
            for (int mf = 0; mf < 8; ++mf) af[mf] = frag_ld64(pA, wm * 128 + mf * 16 + lr, k2b);
#pragma unroll
            for (int nf = 0; nf < 4; ++nf) bfr[nf] = frag_ld64(pB, wn * 64 + nf * 16 + lr, k2b);
#pragma unroll
            for (int mf = 0; mf < 8; ++mf)
#pragma unroll
                for (int nf = 0; nf < 4; ++nf)
                    acc[mf][nf] = __builtin_amdgcn_mfma_f32_16x16x32_bf16(af[mf], bfr[nf], acc[mf][nf], 0, 0, 0);
        }
        __syncthreads();
        cur ^= 1;
    }

    // epilogue: C/D layout col = lane&15, row = (lane>>4)*4 + reg
    int gi = gi0 + wm * 128, gj = gj0 + wn * 64;
    int rbase = (lane >> 4) << 2;
    float sj[4];
#pragma unroll
    for (int nf = 0; nf < 4; ++nf) sj[nf] = sq[gj + nf * 16 + lr];

    float mmax = 0.f, mmin = 3e38f;
#pragma unroll
    for (int mf = 0; mf < 8; ++mf)
#pragma unroll
        for (int r = 0; r < 4; ++r) {
            int i = gi + mf * 16 + rbase + r;
            float si = sq[i];
#pragma unroll
            for (int nf = 0; nf < 4; ++nf) {
                int j = gj + nf * 16 + lr;
                if (j > i) {
                    float d = si + sj[nf] - 2.0f * acc[mf][nf][r];
                    mmax = fmaxf(mmax, d);
                    mmin = fminf(mmin, d);
                }
            }
        }
    for (int off = 32; off > 0; off >>= 1) {
        mmax = fmaxf(mmax, __shfl_xor(mmax, off, 64));
        mmin = fminf(mmin, __shfl_xor(mmin, off, 64));
    }
    __syncthreads();
    float* red = (float*)P;
    if (lane == 0) { red[w * 2] = mmax; red[w * 2 + 1] = mmin; }
    __syncthreads();
    if (tid == 0) {
        float M = red[0], m = red[1];
#pragma unroll
        for (int q = 1; q < 8; ++q) { M = fmaxf(M, red[q * 2]); m = fminf(m, red[q * 2 + 1]); }
        atomicMax(tmax, __float_as_uint(M));   // d >= 0, bit-compare valid
        blockmin[L] = m;
    }
}

// ---------------- PASS 2: exact (3-plane) edges, only on candidate blocks ----------------
__global__ __launch_bounds__(256) void edges_kernel(const unsigned short* __restrict__ Xh,
                                                    const unsigned short* __restrict__ Xl,
                                                    const float* __restrict__ sq,
                                                    const unsigned* __restrict__ tmax,
                                                    const float* __restrict__ blockmin,
                                                    unsigned* __restrict__ cnt,
                                                    int2* __restrict__ edges,
                                                    float* __restrict__ deg) {
    int L = (blockIdx.x % 8) * (TRI2 / 8) + blockIdx.x / 8;
    int bi, bj;
    tri_decode(L, NBT, bi, bj);
    // parent 256-tile min (conservative: parent min <= any child's valid-pair min)
    int pbi = bi >> 1, pbj = bj >> 1;
    int pL = pbi * NBT2 - pbi * (pbi - 1) / 2 + (pbj - pbi);
    float t = 0.5f * __uint_as_float(*tmax);
    if (!(blockmin[pL] < t + MARGIN)) return;

    __shared__ __align__(16) unsigned short planes[4][BT][32];  // Ah, Al, Bh, Bl = 32 KB

    int tid = threadIdx.x;
    int w = tid >> 6;
    int wm = w >> 1, wn = w & 1;
    int lane = tid & 63;
    int lr = lane & 15;
    int k2b = (lane >> 4) << 4;

    int gi0 = bi * BT, gj0 = bj * BT;

    const unsigned short* srcbase = (w & 1) ? Xl : Xh;
    int grow0 = (w < 2) ? gi0 : gj0;
    unsigned short* plane_w = &planes[w][0][0];

    int srow = lane >> 2;
    int sk2 = ((lane & 3) << 4);

    f32x4 acc[4][4] = {};

    for (int kc = 0; kc < K2; kc += 32) {
        __syncthreads();
#pragma unroll
        for (int c = 0; c < 8; ++c) {
            int row = c * 16 + srow;
            int k2 = sk2 ^ (((row >> 1) & 3) << 4);
            const char* g = (const char*)(srcbase + (size_t)(grow0 + row) * K2 + kc) + k2;
            __builtin_amdgcn_global_load_lds((const void*)g, (void*)((char*)plane_w + c * 1024), 16, 0, 0);
        }
        __syncthreads();

        bf16x8 ahf[4], alf[4], bhf[4], blf[4];
#pragma unroll
        for (int mf = 0; mf < 4; ++mf) {
            int r = wm * 64 + mf * 16 + lr;
            ahf[mf] = frag_ld32(&planes[0][0][0], r, k2b);
            alf[mf] = frag_ld32(&planes[1][0][0], r, k2b);
        }
#pragma unroll
        for (int nf = 0; nf < 4; ++nf) {
            int r = wn * 64 + nf * 16 + lr;
            bhf[nf] = frag_ld32(&planes[2][0][0], r, k2b);
            blf[nf] = frag_ld32(&planes[3][0][0], r, k2b);
        }
#pragma unroll
        for (int mf = 0; mf < 4; ++mf)
#pragma unroll
            for (int nf = 0; nf < 4; ++nf) {
                acc[mf][nf] = __builtin_amdgcn_mfma_f32_16x16x32_bf16(ahf[mf], bhf[nf], acc[mf][nf], 0, 0, 0);
                acc[mf][nf] = __builtin_amdgcn_mfma_f32_16x16x32_bf16(ahf[mf], blf[nf], acc[mf][nf], 0, 0, 0);
                acc[mf][nf] = __builtin_amdgcn_mfma_f32_16x16x32_bf16(alf[mf], bhf[nf], acc[mf][nf], 0, 0, 0);
            }
    }

    int gi = gi0 + wm * 64, gj = gj0 + wn * 64;
    int rbase = (lane >> 4) << 2;
    float sj[4];
#pragma unroll
    for (int nf = 0; nf < 4; ++nf) sj[nf] = sq[gj + nf * 16 + lr];

#pragma unroll
    for (int mf = 0; mf < 4; ++mf)
#pragma unroll
        for (int r = 0; r < 4; ++r) {
            int i = gi + mf * 16 + rbase + r;
            float si = sq[i];
#pragma unroll
            for (int nf = 0; nf < 4; ++nf) {
                int j = gj + nf * 16 + lr;
                if (j > i) {
                    float d = si + sj[nf] - 2.0f * acc[mf][nf][r];
                    if (d < t) {
                        unsigned p = atomicAdd(cnt, 1u);
                        if (p < (unsigned)CAP) edges[p] = make_int2(i, j);
                        atomicAdd(&deg[j], 1.0f);
                    }
                }
            }
        }
}

// ---------------- MFMA GEMM 64x64 tiles (dbuf): H = A[M][Kp] @ Wt[256][Kp]^T ----------------
__global__ __launch_bounds__(256) void gemm_mfma_kernel(const unsigned short* __restrict__ A,
                                                        const unsigned short* __restrict__ Wt,
                                                        float* __restrict__ H, int Kp) {
    __shared__ __align__(16) unsigned short P[2][2][64][32];  // dbuf x {A,B} = 16 KB
    int bm = blockIdx.x, bn = blockIdx.y;
    int tid = threadIdx.x;
    int w = tid >> 6;
    int wm = w >> 1, wn = w & 1;      // 2x2 waves, 32x32 each
    int lane = tid & 63;
    int lr = lane & 15;
    int k2b = (lane >> 4) << 4;

    int gm0 = bm * 64, gn0 = bn * 64;

    const unsigned short* srcbase = (w < 2) ? A + (size_t)gm0 * Kp : Wt + (size_t)gn0 * Kp;
    int pidx = (w < 2) ? 0 : 1;
    int rowbase = (w & 1) * 32;
    int sr = lane >> 2;               // 0..15
    int ss = lane & 3;                // 0..3
    int kb = ((ss ^ ((sr >> 1) & 3)) << 4);

    auto STAGE = [&](int buf, int kc) {
        char* dst = (char*)&P[buf][pidx][0][0] + rowbase * 64;
#pragma unroll
        for (int c = 0; c < 2; ++c) {
            int row = rowbase + c * 16 + sr;
            const char* g = (const char*)srcbase + ((size_t)row * Kp + kc) * 2 + kb;
            __builtin_amdgcn_global_load_lds((const void*)g, (void*)(dst + c * 1024), 16, 0, 0);
        }
    };

    f32x4 acc[2][2] = {};

    STAGE(0, 0);
    __syncthreads();
    int cur = 0;
    int nt = Kp / 32;
    for (int t = 0; t < nt; ++t) {
        if (t < nt - 1) STAGE(cur ^ 1, (t + 1) * 32);
        const unsigned short* pA = &P[cur][0][0][0];
        const unsigned short* pB = &P[cur][1][0][0];
        bf16x8 af[2], bfr[2];
#pragma unroll
        for (int mf = 0; mf < 2; ++mf) af[mf] = frag_ld32(pA, wm * 32 + mf * 16 + lr, k2b);
#pragma unroll
        for (int nf = 0; nf < 2; ++nf) bfr[nf] = frag_ld32(pB, wn * 32 + nf * 16 + lr, k2b);
#pragma unroll
        for (int mf = 0; mf < 2; ++mf)
#pragma unroll
            for (int nf = 0; nf < 2; ++nf)
                acc[mf][nf] = __builtin_amdgcn_mfma_f32_16x16x32_bf16(af[mf], bfr[nf], acc[mf][nf], 0, 0, 0);
        __syncthreads();
        cur ^= 1;
    }

    int rbase = (lane >> 4) << 2;
#pragma unroll
    for (int mf = 0; mf < 2; ++mf)
#pragma unroll
        for (int r = 0; r < 4; ++r) {
            int row = gm0 + wm * 32 + mf * 16 + rbase + r;
#pragma unroll
            for (int nf = 0; nf < 2; ++nf) {
                int col = gn0 + wn * 32 + nf * 16 + lr;
                H[(size_t)row * NH + col] = acc[mf][nf][r];
            }
        }
}

// ---------------- fused aggregate + bias + relu + bf16 cast + pool ----------------
#define ECAP 256
__global__ void relupool2_kernel(const float* __restrict__ H, const float* __restrict__ deg,
                                 const int2* __restrict__ edges, const unsigned* __restrict__ cnt,
                                 const float* __restrict__ b, unsigned short* __restrict__ Xb,
                                 float* __restrict__ psum) {
    __shared__ int lcnt;
    __shared__ int lsrc[ECAP];
    __shared__ short ltgt[ECAP];
    __shared__ float lw[ECAP];
    int f = threadIdx.x;
    int i0 = blockIdx.x * 64;
    if (f == 0) lcnt = 0;
    __syncthreads();
    unsigned n = *cnt;
    if (n > (unsigned)CAP) n = CAP;
    for (unsigned e = f; e < n; e += 256) {
        int2 ij = edges[e];
        if (ij.y >= i0 && ij.y < i0 + 64) {
            int p = atomicAdd(&lcnt, 1);
            if (p < ECAP) {
                lsrc[p] = ij.x;
                ltgt[p] = (short)(ij.y - i0);
                lw[p] = (1.0f / sqrtf(deg[ij.x])) * (1.0f / sqrtf(deg[ij.y]));
            }
        }
    }
    __syncthreads();
    int m = lcnt < ECAP ? lcnt : ECAP;
    float bias = b[f];
    float s = 0.f;
    for (int r = 0; r < 64; r++) {
        int row = i0 + r;
        float v = H[(size_t)row * NH + f] / deg[row];   // dinv^2 = 1/deg
        for (int p = 0; p < m; ++p)
            if (ltgt[p] == r) v += lw[p] * H[(size_t)lsrc[p] * NH + f];
        v = fmaxf(v + bias, 0.f);
        Xb[(size_t)row * NH + f] = f32_to_bf16(v);
        s += v;
    }
    atomicAdd(&psum[f], s);
}

__global__ void finalize_kernel(const float* __restrict__ psum, float* __restrict__ out) {
    int f = threadIdx.x;
    float p = (psum[f] + psum[NH + f] + psum[2 * NH + f]) * (1.0f / (float)N);
    out[f] = p;
    out[NH + f] = p;
}

static inline size_t align_up(size_t x, size_t a) { return (x + a - 1) & ~(a - 1); }

extern "C" void kernel_launch(void* const* d_in, const int* in_sizes, int n_in,
                              void* d_out, int out_size, void* d_ws, size_t ws_size,
                              hipStream_t stream) {
    const float* feature = (const float*)d_in[0];
    const float* W1 = (const float*)d_in[1];
    const float* b1 = (const float*)d_in[2];
    const float* W2 = (const float*)d_in[3];
    const float* b2 = (const float*)d_in[4];
    const float* W3 = (const float*)d_in[5];
    const float* b3 = (const float*)d_in[6];
    float* out = (float*)d_out;

    char* w = (char*)d_ws;
    size_t off = 0;
    float* sq = (float*)(w + off);         off += (size_t)N * 4;
    float* deg = (float*)(w + off);        off += (size_t)N * 4;
    float* psum = (float*)(w + off);       off += 3 * NH * 4;
    unsigned* tmax = (unsigned*)(w + off); off += 4;
    unsigned* cnt = (unsigned*)(w + off);  off += 4;
    off = align_up(off, 256);
    float* blockmin = (float*)(w + off);   off += (size_t)TRI2 * 4;
    off = align_up(off, 256);
    int2* edges = (int2*)(w + off);        off += (size_t)CAP * 8;
    off = align_up(off, 256);
    float* H = (float*)(w + off);          off += (size_t)N * NH * 4;
    off = align_up(off, 256);
    unsigned short* Xh = (unsigned short*)(w + off);  off += (size_t)N * K2 * 2;
    unsigned short* Xl = (unsigned short*)(w + off);  off += (size_t)N * K2 * 2;
    unsigned short* Wt1 = (unsigned short*)(w + off); off += (size_t)NH * K2 * 2;
    unsigned short* Wt2 = (unsigned short*)(w + off); off += (size_t)NH * NH * 2;
    unsigned short* Wt3 = (unsigned short*)(w + off); off += (size_t)NH * NH * 2;
    unsigned short* Xb = (unsigned short*)(w + off);  off += (size_t)N * NH * 2;

    prep_kernel<<<N, 256, 0, stream>>>(feature, Xh, Xl, sq, deg, psum, tmax, cnt);
    wconv3_kernel<<<dim3(NH, 3), 256, 0, stream>>>(W1, W2, W3, Wt1, Wt2, Wt3);
    distmax_kernel<<<TRI256, 512, 0, stream>>>(Xh, sq, tmax, blockmin);
    edges_kernel<<<TRI2, 256, 0, stream>>>(Xh, Xl, sq, tmax, blockmin, cnt, edges, deg);

    // layer 1
    gemm_mfma_kernel<<<dim3(N / 64, NH / 64), 256, 0, stream>>>(Xh, Wt1, H, K2);
    relupool2_kernel<<<N / 64, NH, 0, stream>>>(H, deg, edges, cnt, b1, Xb, psum);

    // layer 2
    gemm_mfma_kernel<<<dim3(N / 64, NH / 64), 256, 0, stream>>>(Xb, Wt2, H, NH);
    relupool2_kernel<<<N / 64, NH, 0, stream>>>(H, deg, edges, cnt, b2, Xb, psum + NH);

    // layer 3
    gemm_mfma_kernel<<<dim3(N / 64, NH / 64), 256, 0, stream>>>(Xb, Wt3, H, NH);
    relupool2_kernel<<<N / 64, NH, 0, stream>>>(H, deg, edges, cnt, b3, Xb, psum + 2 * NH);

    finalize_kernel<<<1, NH, 0, stream>>>(psum, out);
}

// Round 7
// 160.853 us; speedup vs baseline: 6.9095x; 1.0077x over previous
//
#include <hip/hip_runtime.h>

#define N 8192
#define F 500
#define K2 512                        // F padded to MFMA-friendly K
#define NH 256
#define CAP (1 << 17)
#define BT 128                        // pass-2 tile
#define NBT (N / BT)                  // 64
#define TRI2 (NBT * (NBT + 1) / 2)    // 2080
#define BT2 256                       // pass-1 tile
#define NBT2 (N / BT2)                // 32
#define TRI256 (NBT2 * (NBT2 + 1) / 2)  // 528
#define MARGIN 2.0f                   // |d_hi - d_exact| safety bound

using bf16x8 = __attribute__((ext_vector_type(8))) short;
using f32x4  = __attribute__((ext_vector_type(4))) float;

__device__ __forceinline__ unsigned short f32_to_bf16(float x) {
    unsigned u = __float_as_uint(x);
    u += 0x7fffu + ((u >> 16) & 1u);   // RTNE
    return (unsigned short)(u >> 16);
}
__device__ __forceinline__ float bf16_to_f32(unsigned short h) {
    return __uint_as_float(((unsigned)h) << 16);
}

// KS=32 plane: [rows][32 bf16] (64 B rows), 2-bit XOR swizzle
__device__ __forceinline__ bf16x8 frag_ld32(const unsigned short* plane, int r, int k2b) {
    int k2 = k2b ^ (((r >> 1) & 3) << 4);
    return *(const bf16x8*)((const char*)plane + r * 64 + k2);
}
// KS=64 plane: [rows][64 bf16] (128 B rows), 3-bit XOR swizzle (slot ^= r&7)
__device__ __forceinline__ bf16x8 frag_ld64(const unsigned short* plane, int r, int k2b) {
    int k2 = k2b ^ ((r & 7) << 4);
    return *(const bf16x8*)((const char*)plane + r * 128 + k2);
}

// ---------------- prep (blocks < N) + wconv (blocks >= N) ----------------
__global__ void prep_kernel(const float* __restrict__ X,
                            const float* __restrict__ W1, const float* __restrict__ W2,
                            const float* __restrict__ W3,
                            unsigned short* __restrict__ Xh, unsigned short* __restrict__ Xl,
                            float* __restrict__ sq, float* __restrict__ deg,
                            float* __restrict__ psum, unsigned* __restrict__ tmax,
                            unsigned* __restrict__ cnt,
                            unsigned short* __restrict__ Wt1, unsigned short* __restrict__ Wt2,
                            unsigned short* __restrict__ Wt3) {
    int bid = blockIdx.x;
    if (bid >= N) {   // weight transpose+convert
        int q = bid - N;
        int n = q & (NH - 1), which = q >> 8;
        const float* W = which == 0 ? W1 : (which == 1 ? W2 : W3);
        unsigned short* Wt = which == 0 ? Wt1 : (which == 1 ? Wt2 : Wt3);
        int K = which == 0 ? F : NH;
        int Kp = which == 0 ? K2 : NH;
        for (int k = threadIdx.x; k < Kp; k += 256) {
            float v = (k < K) ? W[(size_t)k * NH + n] : 0.f;
            Wt[(size_t)n * Kp + k] = f32_to_bf16(v);
        }
        return;
    }
    __shared__ float red[256];
    int i = bid;
    if (threadIdx.x == 0) deg[i] = 1.0f;     // self-loop
    if (i == 0) {
        for (int k = threadIdx.x; k < 3 * NH; k += 256) psum[k] = 0.f;
        if (threadIdx.x == 0) { *tmax = 0u; *cnt = 0u; }
    }
    float s = 0.f;
    for (int k = threadIdx.x; k < K2; k += 256) {
        float x = (k < F) ? X[(size_t)i * F + k] : 0.f;
        unsigned short h = f32_to_bf16(x);
        float r = x - bf16_to_f32(h);
        Xh[(size_t)i * K2 + k] = h;
        Xl[(size_t)i * K2 + k] = f32_to_bf16(r);
        s += x * x;
    }
    red[threadIdx.x] = s;
    __syncthreads();
    for (int off = 128; off > 0; off >>= 1) {
        if (threadIdx.x < off) red[threadIdx.x] += red[threadIdx.x + off];
        __syncthreads();
    }
    if (threadIdx.x == 0) sq[i] = red[0];
}

// ---------------- triangular block decode (nb x nb upper-tri) ----------------
__device__ __forceinline__ void tri_decode(int L, int nb, int& bi, int& bj) {
    float a = (float)(2 * nb + 1);
    bi = (int)((a - sqrtf(a * a - 8.0f * (float)L)) * 0.5f);
    if (bi < 0) bi = 0;
    if (bi > nb - 1) bi = nb - 1;
    while (bi > 0 && bi * nb - bi * (bi - 1) / 2 > L) --bi;
    while (bi < nb - 1 && (bi + 1) * nb - (bi + 1) * bi / 2 <= L) ++bi;
    bj = bi + (L - (bi * nb - bi * (bi - 1) / 2));
}

// ---------------- PASS 1: 256^2 tile, hi-plane distances, counted-vmcnt pipeline ----------------
__global__ __launch_bounds__(512, 2) void distmax_kernel(const unsigned short* __restrict__ Xh,
                                                         const float* __restrict__ sq,
                                                         unsigned* __restrict__ tmax,
                                                         float* __restrict__ blockmin) {
    int L = (blockIdx.x % 8) * (TRI256 / 8) + blockIdx.x / 8;  // XCD swizzle (528%8==0)
    int bi, bj;
    tri_decode(L, NBT2, bi, bj);

    __shared__ __align__(16) unsigned short P[2][2][BT2][64];  // [buf][A/B][row][k] = 128 KB

    int tid = threadIdx.x;
    int w = tid >> 6;                 // 8 waves: 2 (M) x 4 (N)
    int wm = w >> 2, wn = w & 3;
    int lane = tid & 63;
    int lr = lane & 15;

    int gi0 = bi * BT2, gj0 = bj * BT2;

    // staging: waves 0-3 stage A plane (64-row quarters), waves 4-7 stage B plane
    const unsigned short* srcb = (w < 4) ? Xh + (size_t)gi0 * K2 : Xh + (size_t)gj0 * K2;
    int pidx = w >> 2;
    int rowbase = (w & 3) * 64;
    int sr = lane >> 3;          // row-in-chunk 0..7
    int ss = lane & 7;           // slot 0..7
    int kb = ((ss ^ sr) << 4);   // pre-swizzled k-byte within 128-B row

    auto STAGE = [&](int buf, int kc) {   // 8 global_load_lds per wave (vmcnt +8)
        char* dst = (char*)&P[buf][pidx][0][0] + rowbase * 128;
#pragma unroll
        for (int c = 0; c < 8; ++c) {
            int row = rowbase + c * 8 + sr;
            const char* g = (const char*)(srcb + (size_t)row * K2 + kc) + kb;
            __builtin_amdgcn_global_load_lds((const void*)g, (void*)(dst + c * 1024), 16, 0, 0);
        }
    };

    f32x4 acc[8][4] = {};

    STAGE(0, 0);
    STAGE(1, 64);
#pragma unroll
    for (int t = 0; t < K2 / 64; ++t) {
        const int c = t & 1;
        if (t < K2 / 64 - 1) { asm volatile("s_waitcnt vmcnt(8)" ::: "memory"); }
        else                 { asm volatile("s_waitcnt vmcnt(0)" ::: "memory"); }
        __builtin_amdgcn_sched_barrier(0);
        __builtin_amdgcn_s_barrier();          // buf c landed for all waves
        const unsigned short* pA = &P[c][0][0][0];
        const unsigned short* pB = &P[c][1][0][0];
#pragma unroll
        for (int ks = 0; ks < 2; ++ks) {
            int k2b = ks * 64 + ((lane >> 4) << 4);
            bf16x8 af[8], bfr[4];
#pragma unroll
            for (int mf = 0; mf < 8; ++mf) af[mf] = frag_ld64(pA, wm * 128 + mf * 16 + lr, k2b);
#pragma unroll
            for (int nf = 0; nf < 4; ++nf) bfr[nf] = frag_ld64(pB, wn * 64 + nf * 16 + lr, k2b);
            __builtin_amdgcn_s_setprio(1);
#pragma unroll
            for (int mf = 0; mf < 8; ++mf)
#pragma unroll
                for (int nf = 0; nf < 4; ++nf)
                    acc[mf][nf] = __builtin_amdgcn_mfma_f32_16x16x32_bf16(af[mf], bfr[nf], acc[mf][nf], 0, 0, 0);
            __builtin_amdgcn_s_setprio(0);
        }
        asm volatile("s_waitcnt lgkmcnt(0)" ::: "memory");
        __builtin_amdgcn_sched_barrier(0);
        __builtin_amdgcn_s_barrier();          // all waves done reading buf c
        if (t + 2 < K2 / 64) STAGE(c, (t + 2) * 64);   // overwrite buf c; stays in flight
    }

    // epilogue: C/D layout col = lane&15, row = (lane>>4)*4 + reg
    int gi = gi0 + wm * 128, gj = gj0 + wn * 64;
    int rbase = (lane >> 4) << 2;
    float sj[4];
#pragma unroll
    for (int nf = 0; nf < 4; ++nf) sj[nf] = sq[gj + nf * 16 + lr];

    float mmax = 0.f, mmin = 3e38f;
#pragma unroll
    for (int mf = 0; mf < 8; ++mf)
#pragma unroll
        for (int r = 0; r < 4; ++r) {
            int i = gi + mf * 16 + rbase + r;
            float si = sq[i];
#pragma unroll
            for (int nf = 0; nf < 4; ++nf) {
                int j = gj + nf * 16 + lr;
                if (j > i) {
                    float d = si + sj[nf] - 2.0f * acc[mf][nf][r];
                    mmax = fmaxf(mmax, d);
                    mmin = fminf(mmin, d);
                }
            }
        }
    for (int off = 32; off > 0; off >>= 1) {
        mmax = fmaxf(mmax, __shfl_xor(mmax, off, 64));
        mmin = fminf(mmin, __shfl_xor(mmin, off, 64));
    }
    __syncthreads();
    float* red = (float*)P;
    if (lane == 0) { red[w * 2] = mmax; red[w * 2 + 1] = mmin; }
    __syncthreads();
    if (tid == 0) {
        float M = red[0], m = red[1];
#pragma unroll
        for (int q = 1; q < 8; ++q) { M = fmaxf(M, red[q * 2]); m = fminf(m, red[q * 2 + 1]); }
        atomicMax(tmax, __float_as_uint(M));   // d >= 0, bit-compare valid
        blockmin[L] = m;
    }
}

// ---------------- PASS 2: exact (3-plane) edges, only on candidate blocks ----------------
__global__ __launch_bounds__(256) void edges_kernel(const unsigned short* __restrict__ Xh,
                                                    const unsigned short* __restrict__ Xl,
                                                    const float* __restrict__ sq,
                                                    const unsigned* __restrict__ tmax,
                                                    const float* __restrict__ blockmin,
                                                    unsigned* __restrict__ cnt,
                                                    int2* __restrict__ edges,
                                                    float* __restrict__ deg) {
    int L = (blockIdx.x % 8) * (TRI2 / 8) + blockIdx.x / 8;
    int bi, bj;
    tri_decode(L, NBT, bi, bj);
    // parent 256-tile min (conservative: parent min <= any child's valid-pair min)
    int pbi = bi >> 1, pbj = bj >> 1;
    int pL = pbi * NBT2 - pbi * (pbi - 1) / 2 + (pbj - pbi);
    float t = 0.5f * __uint_as_float(*tmax);
    if (!(blockmin[pL] < t + MARGIN)) return;

    __shared__ __align__(16) unsigned short planes[4][BT][32];  // Ah, Al, Bh, Bl = 32 KB

    int tid = threadIdx.x;
    int w = tid >> 6;
    int wm = w >> 1, wn = w & 1;
    int lane = tid & 63;
    int lr = lane & 15;
    int k2b = (lane >> 4) << 4;

    int gi0 = bi * BT, gj0 = bj * BT;

    const unsigned short* srcbase = (w & 1) ? Xl : Xh;
    int grow0 = (w < 2) ? gi0 : gj0;
    unsigned short* plane_w = &planes[w][0][0];

    int srow = lane >> 2;
    int sk2 = ((lane & 3) << 4);

    f32x4 acc[4][4] = {};

    for (int kc = 0; kc < K2; kc += 32) {
        __syncthreads();
#pragma unroll
        for (int c = 0; c < 8; ++c) {
            int row = c * 16 + srow;
            int k2 = sk2 ^ (((row >> 1) & 3) << 4);
            const char* g = (const char*)(srcbase + (size_t)(grow0 + row) * K2 + kc) + k2;
            __builtin_amdgcn_global_load_lds((const void*)g, (void*)((char*)plane_w + c * 1024), 16, 0, 0);
        }
        __syncthreads();

        bf16x8 ahf[4], alf[4], bhf[4], blf[4];
#pragma unroll
        for (int mf = 0; mf < 4; ++mf) {
            int r = wm * 64 + mf * 16 + lr;
            ahf[mf] = frag_ld32(&planes[0][0][0], r, k2b);
            alf[mf] = frag_ld32(&planes[1][0][0], r, k2b);
        }
#pragma unroll
        for (int nf = 0; nf < 4; ++nf) {
            int r = wn * 64 + nf * 16 + lr;
            bhf[nf] = frag_ld32(&planes[2][0][0], r, k2b);
            blf[nf] = frag_ld32(&planes[3][0][0], r, k2b);
        }
#pragma unroll
        for (int mf = 0; mf < 4; ++mf)
#pragma unroll
            for (int nf = 0; nf < 4; ++nf) {
                acc[mf][nf] = __builtin_amdgcn_mfma_f32_16x16x32_bf16(ahf[mf], bhf[nf], acc[mf][nf], 0, 0, 0);
                acc[mf][nf] = __builtin_amdgcn_mfma_f32_16x16x32_bf16(ahf[mf], blf[nf], acc[mf][nf], 0, 0, 0);
                acc[mf][nf] = __builtin_amdgcn_mfma_f32_16x16x32_bf16(alf[mf], bhf[nf], acc[mf][nf], 0, 0, 0);
            }
    }

    int gi = gi0 + wm * 64, gj = gj0 + wn * 64;
    int rbase = (lane >> 4) << 2;
    float sj[4];
#pragma unroll
    for (int nf = 0; nf < 4; ++nf) sj[nf] = sq[gj + nf * 16 + lr];

#pragma unroll
    for (int mf = 0; mf < 4; ++mf)
#pragma unroll
        for (int r = 0; r < 4; ++r) {
            int i = gi + mf * 16 + rbase + r;
            float si = sq[i];
#pragma unroll
            for (int nf = 0; nf < 4; ++nf) {
                int j = gj + nf * 16 + lr;
                if (j > i) {
                    float d = si + sj[nf] - 2.0f * acc[mf][nf][r];
                    if (d < t) {
                        unsigned p = atomicAdd(cnt, 1u);
                        if (p < (unsigned)CAP) edges[p] = make_int2(i, j);
                        atomicAdd(&deg[j], 1.0f);
                    }
                }
            }
        }
}

// ---------------- MFMA GEMM 64x64 tiles, counted-vmcnt pipeline ----------------
__global__ __launch_bounds__(256) void gemm_mfma_kernel(const unsigned short* __restrict__ A,
                                                        const unsigned short* __restrict__ Wt,
                                                        float* __restrict__ H, int Kp) {
    __shared__ __align__(16) unsigned short P[2][2][64][32];  // [buf][A/B] = 16 KB
    int bm = blockIdx.x, bn = blockIdx.y;
    int tid = threadIdx.x;
    int w = tid >> 6;
    int wm = w >> 1, wn = w & 1;      // 2x2 waves, 32x32 each
    int lane = tid & 63;
    int lr = lane & 15;
    int k2b = (lane >> 4) << 4;

    int gm0 = bm * 64, gn0 = bn * 64;

    const unsigned short* srcbase = (w < 2) ? A + (size_t)gm0 * Kp : Wt + (size_t)gn0 * Kp;
    int pidx = (w < 2) ? 0 : 1;
    int rowbase = (w & 1) * 32;
    int sr = lane >> 2;               // 0..15
    int ss = lane & 3;                // 0..3
    int kb = ((ss ^ ((sr >> 1) & 3)) << 4);

    auto STAGE = [&](int buf, int kc) {   // 2 global_load_lds per wave (vmcnt +2)
        char* dst = (char*)&P[buf][pidx][0][0] + rowbase * 64;
#pragma unroll
        for (int c = 0; c < 2; ++c) {
            int row = rowbase + c * 16 + sr;
            const char* g = (const char*)srcbase + ((size_t)row * Kp + kc) * 2 + kb;
            __builtin_amdgcn_global_load_lds((const void*)g, (void*)(dst + c * 1024), 16, 0, 0);
        }
    };

    f32x4 acc[2][2] = {};

    int nt = Kp / 32;
    STAGE(0, 0);
    STAGE(1, 32);
    for (int t = 0; t < nt; ++t) {
        const int c = t & 1;
        if (t < nt - 1) { asm volatile("s_waitcnt vmcnt(2)" ::: "memory"); }
        else            { asm volatile("s_waitcnt vmcnt(0)" ::: "memory"); }
        __builtin_amdgcn_sched_barrier(0);
        __builtin_amdgcn_s_barrier();
        const unsigned short* pA = &P[c][0][0][0];
        const unsigned short* pB = &P[c][1][0][0];
        bf16x8 af[2], bfr[2];
#pragma unroll
        for (int mf = 0; mf < 2; ++mf) af[mf] = frag_ld32(pA, wm * 32 + mf * 16 + lr, k2b);
#pragma unroll
        for (int nf = 0; nf < 2; ++nf) bfr[nf] = frag_ld32(pB, wn * 32 + nf * 16 + lr, k2b);
        __builtin_amdgcn_s_setprio(1);
#pragma unroll
        for (int mf = 0; mf < 2; ++mf)
#pragma unroll
            for (int nf = 0; nf < 2; ++nf)
                acc[mf][nf] = __builtin_amdgcn_mfma_f32_16x16x32_bf16(af[mf], bfr[nf], acc[mf][nf], 0, 0, 0);
        __builtin_amdgcn_s_setprio(0);
        asm volatile("s_waitcnt lgkmcnt(0)" ::: "memory");
        __builtin_amdgcn_sched_barrier(0);
        __builtin_amdgcn_s_barrier();
        if (t + 2 < nt) STAGE(c, (t + 2) * 32);
    }

    int rbase = (lane >> 4) << 2;
#pragma unroll
    for (int mf = 0; mf < 2; ++mf)
#pragma unroll
        for (int r = 0; r < 4; ++r) {
            int row = gm0 + wm * 32 + mf * 16 + rbase + r;
#pragma unroll
            for (int nf = 0; nf < 2; ++nf) {
                int col = gn0 + wn * 32 + nf * 16 + lr;
                H[(size_t)row * NH + col] = acc[mf][nf][r];
            }
        }
}

// ---------------- fused aggregate + bias + relu + bf16 cast + pool ----------------
#define ECAP 256
__global__ void relupool2_kernel(const float* __restrict__ H, const float* __restrict__ deg,
                                 const int2* __restrict__ edges, const unsigned* __restrict__ cnt,
                                 const float* __restrict__ b, unsigned short* __restrict__ Xb,
                                 float* __restrict__ psum) {
    __shared__ int lcnt;
    __shared__ int lsrc[ECAP];
    __shared__ short ltgt[ECAP];
    __shared__ float lw[ECAP];
    int f = threadIdx.x;
    int i0 = blockIdx.x * 64;
    if (f == 0) lcnt = 0;
    __syncthreads();
    unsigned n = *cnt;
    if (n > (unsigned)CAP) n = CAP;
    for (unsigned e = f; e < n; e += 256) {
        int2 ij = edges[e];
        if (ij.y >= i0 && ij.y < i0 + 64) {
            int p = atomicAdd(&lcnt, 1);
            if (p < ECAP) {
                lsrc[p] = ij.x;
                ltgt[p] = (short)(ij.y - i0);
                lw[p] = (1.0f / sqrtf(deg[ij.x])) * (1.0f / sqrtf(deg[ij.y]));
            }
        }
    }
    __syncthreads();
    int m = lcnt < ECAP ? lcnt : ECAP;
    float bias = b[f];
    float s = 0.f;
    for (int r = 0; r < 64; r++) {
        int row = i0 + r;
        float v = H[(size_t)row * NH + f] / deg[row];   // dinv^2 = 1/deg
        for (int p = 0; p < m; ++p)
            if (ltgt[p] == r) v += lw[p] * H[(size_t)lsrc[p] * NH + f];
        v = fmaxf(v + bias, 0.f);
        Xb[(size_t)row * NH + f] = f32_to_bf16(v);
        s += v;
    }
    atomicAdd(&psum[f], s);
}

__global__ void finalize_kernel(const float* __restrict__ psum, float* __restrict__ out) {
    int f = threadIdx.x;
    float p = (psum[f] + psum[NH + f] + psum[2 * NH + f]) * (1.0f / (float)N);
    out[f] = p;
    out[NH + f] = p;
}

static inline size_t align_up(size_t x, size_t a) { return (x + a - 1) & ~(a - 1); }

extern "C" void kernel_launch(void* const* d_in, const int* in_sizes, int n_in,
                              void* d_out, int out_size, void* d_ws, size_t ws_size,
                              hipStream_t stream) {
    const float* feature = (const float*)d_in[0];
    const float* W1 = (const float*)d_in[1];
    const float* b1 = (const float*)d_in[2];
    const float* W2 = (const float*)d_in[3];
    const float* b2 = (const float*)d_in[4];
    const float* W3 = (const float*)d_in[5];
    const float* b3 = (const float*)d_in[6];
    float* out = (float*)d_out;

    char* w = (char*)d_ws;
    size_t off = 0;
    float* sq = (float*)(w + off);         off += (size_t)N * 4;
    float* deg = (float*)(w + off);        off += (size_t)N * 4;
    float* psum = (float*)(w + off);       off += 3 * NH * 4;
    unsigned* tmax = (unsigned*)(w + off); off += 4;
    unsigned* cnt = (unsigned*)(w + off);  off += 4;
    off = align_up(off, 256);
    float* blockmin = (float*)(w + off);   off += (size_t)TRI2 * 4;
    off = align_up(off, 256);
    int2* edges = (int2*)(w + off);        off += (size_t)CAP * 8;
    off = align_up(off, 256);
    float* H = (float*)(w + off);          off += (size_t)N * NH * 4;
    off = align_up(off, 256);
    unsigned short* Xh = (unsigned short*)(w + off);  off += (size_t)N * K2 * 2;
    unsigned short* Xl = (unsigned short*)(w + off);  off += (size_t)N * K2 * 2;
    unsigned short* Wt1 = (unsigned short*)(w + off); off += (size_t)NH * K2 * 2;
    unsigned short* Wt2 = (unsigned short*)(w + off); off += (size_t)NH * NH * 2;
    unsigned short* Wt3 = (unsigned short*)(w + off); off += (size_t)NH * NH * 2;
    unsigned short* Xb = (unsigned short*)(w + off);  off += (size_t)N * NH * 2;

    prep_kernel<<<N + 3 * NH, 256, 0, stream>>>(feature, W1, W2, W3, Xh, Xl, sq, deg, psum,
                                                tmax, cnt, Wt1, Wt2, Wt3);
    distmax_kernel<<<TRI256, 512, 0, stream>>>(Xh, sq, tmax, blockmin);
    edges_kernel<<<TRI2, 256, 0, stream>>>(Xh, Xl, sq, tmax, blockmin, cnt, edges, deg);

    // layer 1
    gemm_mfma_kernel<<<dim3(N / 64, NH / 64), 256, 0, stream>>>(Xh, Wt1, H, K2);
    relupool2_kernel<<<N / 64, NH, 0, stream>>>(H, deg, edges, cnt, b1, Xb, psum);

    // layer 2
    gemm_mfma_kernel<<<dim3(N / 64, NH / 64), 256, 0, stream>>>(Xb, Wt2, H, NH);
    relupool2_kernel<<<N / 64, NH, 0, stream>>>(H, deg, edges, cnt, b2, Xb, psum + NH);

    // layer 3
    gemm_mfma_kernel<<<dim3(N / 64, NH / 64), 256, 0, stream>>>(Xb, Wt3, H, NH);
    relupool2_kernel<<<N / 64, NH, 0, stream>>>(H, deg, edges, cnt, b3, Xb, psum + 2 * NH);

    finalize_kernel<<<1, NH, 0, stream>>>(psum, out);
}

// Round 8
// 159.394 us; speedup vs baseline: 6.9727x; 1.0091x over previous
//
#include <hip/hip_runtime.h>

#define N 8192
#define F 500
#define K2 512                        // F padded to MFMA-friendly K
#define NH 256
#define CAP (1 << 17)
#define BT 128                        // pass-2 tile
#define NBT (N / BT)                  // 64
#define TRI2 (NBT * (NBT + 1) / 2)    // 2080
#define BT2 256                       // pass-1 tile
#define NBT2 (N / BT2)                // 32
#define TRI256 (NBT2 * (NBT2 + 1) / 2)  // 528
#define MARGIN 2.0f                   // |d_hi - d_exact| safety bound

using bf16x8 = __attribute__((ext_vector_type(8))) short;
using f32x4  = __attribute__((ext_vector_type(4))) float;

__device__ __forceinline__ unsigned short f32_to_bf16(float x) {
    unsigned u = __float_as_uint(x);
    u += 0x7fffu + ((u >> 16) & 1u);   // RTNE
    return (unsigned short)(u >> 16);
}
__device__ __forceinline__ float bf16_to_f32(unsigned short h) {
    return __uint_as_float(((unsigned)h) << 16);
}

// 32-k plane: [rows][32 bf16] (64 B rows), 2-bit XOR swizzle (slot ^= (r>>1)&3)
__device__ __forceinline__ bf16x8 frag_ld32(const unsigned short* plane, int r, int k2b) {
    int k2 = k2b ^ (((r >> 1) & 3) << 4);
    return *(const bf16x8*)((const char*)plane + r * 64 + k2);
}

// ---------------- prep (blocks < N) + wconv (blocks >= N) ----------------
__global__ void prep_kernel(const float* __restrict__ X,
                            const float* __restrict__ W1, const float* __restrict__ W2,
                            const float* __restrict__ W3,
                            unsigned short* __restrict__ Xh, unsigned short* __restrict__ Xl,
                            float* __restrict__ sq, float* __restrict__ deg,
                            float* __restrict__ psum, unsigned* __restrict__ tmax,
                            unsigned* __restrict__ cnt,
                            unsigned short* __restrict__ Wt1, unsigned short* __restrict__ Wt2,
                            unsigned short* __restrict__ Wt3) {
    int bid = blockIdx.x;
    if (bid >= N) {   // weight transpose+convert
        int q = bid - N;
        int n = q & (NH - 1), which = q >> 8;
        const float* W = which == 0 ? W1 : (which == 1 ? W2 : W3);
        unsigned short* Wt = which == 0 ? Wt1 : (which == 1 ? Wt2 : Wt3);
        int K = which == 0 ? F : NH;
        int Kp = which == 0 ? K2 : NH;
        for (int k = threadIdx.x; k < Kp; k += 256) {
            float v = (k < K) ? W[(size_t)k * NH + n] : 0.f;
            Wt[(size_t)n * Kp + k] = f32_to_bf16(v);
        }
        return;
    }
    __shared__ float red[256];
    int i = bid;
    if (threadIdx.x == 0) deg[i] = 1.0f;     // self-loop
    if (i == 0) {
        for (int k = threadIdx.x; k < 3 * NH; k += 256) psum[k] = 0.f;
        if (threadIdx.x == 0) { *tmax = 0u; *cnt = 0u; }
    }
    float s = 0.f;
    for (int k = threadIdx.x; k < K2; k += 256) {
        float x = (k < F) ? X[(size_t)i * F + k] : 0.f;
        unsigned short h = f32_to_bf16(x);
        float r = x - bf16_to_f32(h);
        Xh[(size_t)i * K2 + k] = h;
        Xl[(size_t)i * K2 + k] = f32_to_bf16(r);
        s += x * x;
    }
    red[threadIdx.x] = s;
    __syncthreads();
    for (int off = 128; off > 0; off >>= 1) {
        if (threadIdx.x < off) red[threadIdx.x] += red[threadIdx.x + off];
        __syncthreads();
    }
    if (threadIdx.x == 0) sq[i] = red[0];
}

// ---------------- triangular block decode (nb x nb upper-tri) ----------------
__device__ __forceinline__ void tri_decode(int L, int nb, int& bi, int& bj) {
    float a = (float)(2 * nb + 1);
    bi = (int)((a - sqrtf(a * a - 8.0f * (float)L)) * 0.5f);
    if (bi < 0) bi = 0;
    if (bi > nb - 1) bi = nb - 1;
    while (bi > 0 && bi * nb - bi * (bi - 1) / 2 > L) --bi;
    while (bi < nb - 1 && (bi + 1) * nb - (bi + 1) * bi / 2 <= L) ++bi;
    bj = bi + (L - (bi * nb - bi * (bi - 1) / 2));
}

// ---------------- PASS 1: 256^2 tile, hi-plane distances, 8-phase schedule ----------------
// LDS: [buf][op A=0/B=1][khalf][row 256][k32]  (half-tile = one (op,khalf) = 16 KB)
// Per K-tile (BK=64): 4 phases, each {ds_read subtile; stage 1 half-tile; bar; lgkm0; 16 MFMA; bar}
// vmcnt(6) once per K-tile (3 half-tiles in flight); never drained mid-loop.
__global__ __launch_bounds__(512, 2) void distmax_kernel(const unsigned short* __restrict__ Xh,
                                                         const float* __restrict__ sq,
                                                         unsigned* __restrict__ tmax,
                                                         float* __restrict__ blockmin) {
    int L = (blockIdx.x % 8) * (TRI256 / 8) + blockIdx.x / 8;  // XCD swizzle (528%8==0)
    int bi, bj;
    tri_decode(L, NBT2, bi, bj);

    __shared__ __align__(16) unsigned short P[2][2][2][BT2][32];  // 128 KB

    int tid = threadIdx.x;
    int w = tid >> 6;                 // 8 waves: 2 (M) x 4 (N)
    int wm = w >> 2, wn = w & 3;
    int lane = tid & 63;
    int lr = lane & 15;
    int k2b = (lane >> 4) << 4;

    int gi0 = bi * BT2, gj0 = bj * BT2;

    // staging: all 8 waves cooperate per half-tile; wave w covers rows [w*32, w*32+32)
    int srw = (lane >> 2);            // row within 16-row chunk
    int slot = lane & 3;              // 16B slot within 64B row

    f32x4 acc[8][4] = {};

    auto STAGE = [&](int tile, int op, int kh) {   // 2 global_load_lds per wave
        const unsigned short* src = Xh + (size_t)(op ? gj0 : gi0) * K2;
        char* dstbase = (char*)&P[tile & 1][op][kh][0][0];
#pragma unroll
        for (int c = 0; c < 2; ++c) {
            int row = w * 32 + c * 16 + srw;
            int gk = ((slot ^ ((row >> 1) & 3)) << 3) + tile * 64 + kh * 32;
            const char* g = (const char*)(src + (size_t)row * K2 + gk);
            __builtin_amdgcn_global_load_lds((const void*)g,
                (void*)(dstbase + (w * 32 + c * 16) * 64), 16, 0, 0);
        }
    };
    auto LDA = [&](bf16x8* af, int tile, int ks, int mh) {
        const unsigned short* plane = &P[tile & 1][0][ks][0][0];
#pragma unroll
        for (int i = 0; i < 4; ++i)
            af[i] = frag_ld32(plane, wm * 128 + (mh * 4 + i) * 16 + lr, k2b);
    };
    auto LDB = [&](bf16x8* bq, int tile, int ks) {
        const unsigned short* plane = &P[tile & 1][1][ks][0][0];
#pragma unroll
        for (int i = 0; i < 4; ++i)
            bq[i] = frag_ld32(plane, wn * 64 + i * 16 + lr, k2b);
    };
    auto MM = [&](bf16x8* af, bf16x8* bq, int mh) {   // 16 MFMA cluster
        __builtin_amdgcn_s_setprio(1);
#pragma unroll
        for (int i = 0; i < 4; ++i)
#pragma unroll
            for (int nf = 0; nf < 4; ++nf)
                acc[mh * 4 + i][nf] =
                    __builtin_amdgcn_mfma_f32_16x16x32_bf16(af[i], bq[nf], acc[mh * 4 + i][nf], 0, 0, 0);
        __builtin_amdgcn_s_setprio(0);
    };
#define LGK0() do { asm volatile("s_waitcnt lgkmcnt(0)" ::: "memory"); \
                    __builtin_amdgcn_sched_barrier(0); } while (0)

    // prologue: tile0 fully (B0,A0,B1,A1) + tile1 (B0,A0,B1) = 7 half-tiles (14 loads/wave)
    STAGE(0, 1, 0); STAGE(0, 0, 0); STAGE(0, 1, 1); STAGE(0, 0, 1);
    STAGE(1, 1, 0); STAGE(1, 0, 0); STAGE(1, 1, 1);
    asm volatile("s_waitcnt vmcnt(6)" ::: "memory");   // tile0 landed; tile1's 3 halves in flight
    __builtin_amdgcn_sched_barrier(0);
    __builtin_amdgcn_s_barrier();

#pragma unroll
    for (int t = 0; t < K2 / 64; ++t) {
        bf16x8 af[4], bq[4];
        // phase q0: (A ks0 lo-half, B ks0); stage (A,k1) of t+1
        LDA(af, t, 0, 0); LDB(bq, t, 0);
        if (t + 1 < K2 / 64) STAGE(t + 1, 0, 1);
        __builtin_amdgcn_s_barrier(); LGK0(); MM(af, bq, 0);
        __builtin_amdgcn_s_barrier();
        // phase q1: (A ks0 hi-half); stage (B,k0) of t+2
        LDA(af, t, 0, 1);
        if (t + 2 < K2 / 64) STAGE(t + 2, 1, 0);
        __builtin_amdgcn_s_barrier(); LGK0(); MM(af, bq, 1);
        __builtin_amdgcn_s_barrier();
        // phase q2: (A ks1 lo-half, B ks1); stage (A,k0) of t+2
        LDA(af, t, 1, 0); LDB(bq, t, 1);
        if (t + 2 < K2 / 64) STAGE(t + 2, 0, 0);
        __builtin_amdgcn_s_barrier(); LGK0(); MM(af, bq, 0);
        __builtin_amdgcn_s_barrier();
        // phase q3: (A ks1 hi-half); stage (B,k1) of t+2
        LDA(af, t, 1, 1);
        if (t + 2 < K2 / 64) STAGE(t + 2, 1, 1);
        __builtin_amdgcn_s_barrier(); LGK0(); MM(af, bq, 1);
        if (t + 2 < K2 / 64)      { asm volatile("s_waitcnt vmcnt(6)" ::: "memory"); __builtin_amdgcn_sched_barrier(0); }
        else if (t + 2 == K2 / 64){ asm volatile("s_waitcnt vmcnt(0)" ::: "memory"); __builtin_amdgcn_sched_barrier(0); }
        __builtin_amdgcn_s_barrier();
    }
#undef LGK0

    // epilogue: C/D layout col = lane&15, row = (lane>>4)*4 + reg
    int gi = gi0 + wm * 128, gj = gj0 + wn * 64;
    int rbase = (lane >> 4) << 2;
    float sj[4];
#pragma unroll
    for (int nf = 0; nf < 4; ++nf) sj[nf] = sq[gj + nf * 16 + lr];

    float mmax = 0.f, mmin = 3e38f;
#pragma unroll
    for (int mf = 0; mf < 8; ++mf)
#pragma unroll
        for (int r = 0; r < 4; ++r) {
            int i = gi + mf * 16 + rbase + r;
            float si = sq[i];
#pragma unroll
            for (int nf = 0; nf < 4; ++nf) {
                int j = gj + nf * 16 + lr;
                if (j > i) {
                    float d = si + sj[nf] - 2.0f * acc[mf][nf][r];
                    mmax = fmaxf(mmax, d);
                    mmin = fminf(mmin, d);
                }
            }
        }
    for (int off = 32; off > 0; off >>= 1) {
        mmax = fmaxf(mmax, __shfl_xor(mmax, off, 64));
        mmin = fminf(mmin, __shfl_xor(mmin, off, 64));
    }
    __syncthreads();
    float* red = (float*)P;
    if (lane == 0) { red[w * 2] = mmax; red[w * 2 + 1] = mmin; }
    __syncthreads();
    if (tid == 0) {
        float M = red[0], m = red[1];
#pragma unroll
        for (int q = 1; q < 8; ++q) { M = fmaxf(M, red[q * 2]); m = fminf(m, red[q * 2 + 1]); }
        atomicMax(tmax, __float_as_uint(M));   // d >= 0, bit-compare valid
        blockmin[L] = m;
    }
}

// ---------------- PASS 2: exact (3-plane) edges, only on candidate blocks ----------------
__global__ __launch_bounds__(256) void edges_kernel(const unsigned short* __restrict__ Xh,
                                                    const unsigned short* __restrict__ Xl,
                                                    const float* __restrict__ sq,
                                                    const unsigned* __restrict__ tmax,
                                                    const float* __restrict__ blockmin,
                                                    unsigned* __restrict__ cnt,
                                                    int2* __restrict__ edges,
                                                    float* __restrict__ deg) {
    int L = (blockIdx.x % 8) * (TRI2 / 8) + blockIdx.x / 8;
    int bi, bj;
    tri_decode(L, NBT, bi, bj);
    // parent 256-tile min (conservative: parent min <= any child's valid-pair min)
    int pbi = bi >> 1, pbj = bj >> 1;
    int pL = pbi * NBT2 - pbi * (pbi - 1) / 2 + (pbj - pbi);
    float t = 0.5f * __uint_as_float(*tmax);
    if (!(blockmin[pL] < t + MARGIN)) return;

    __shared__ __align__(16) unsigned short planes[4][BT][32];  // Ah, Al, Bh, Bl = 32 KB

    int tid = threadIdx.x;
    int w = tid >> 6;
    int wm = w >> 1, wn = w & 1;
    int lane = tid & 63;
    int lr = lane & 15;
    int k2b = (lane >> 4) << 4;

    int gi0 = bi * BT, gj0 = bj * BT;

    const unsigned short* srcbase = (w & 1) ? Xl : Xh;
    int grow0 = (w < 2) ? gi0 : gj0;
    unsigned short* plane_w = &planes[w][0][0];

    int srow = lane >> 2;
    int sk2 = ((lane & 3) << 4);

    f32x4 acc[4][4] = {};

    for (int kc = 0; kc < K2; kc += 32) {
        __syncthreads();
#pragma unroll
        for (int c = 0; c < 8; ++c) {
            int row = c * 16 + srow;
            int k2 = sk2 ^ (((row >> 1) & 3) << 4);
            const char* g = (const char*)(srcbase + (size_t)(grow0 + row) * K2 + kc) + k2;
            __builtin_amdgcn_global_load_lds((const void*)g, (void*)((char*)plane_w + c * 1024), 16, 0, 0);
        }
        __syncthreads();

        bf16x8 ahf[4], alf[4], bhf[4], blf[4];
#pragma unroll
        for (int mf = 0; mf < 4; ++mf) {
            int r = wm * 64 + mf * 16 + lr;
            ahf[mf] = frag_ld32(&planes[0][0][0], r, k2b);
            alf[mf] = frag_ld32(&planes[1][0][0], r, k2b);
        }
#pragma unroll
        for (int nf = 0; nf < 4; ++nf) {
            int r = wn * 64 + nf * 16 + lr;
            bhf[nf] = frag_ld32(&planes[2][0][0], r, k2b);
            blf[nf] = frag_ld32(&planes[3][0][0], r, k2b);
        }
#pragma unroll
        for (int mf = 0; mf < 4; ++mf)
#pragma unroll
            for (int nf = 0; nf < 4; ++nf) {
                acc[mf][nf] = __builtin_amdgcn_mfma_f32_16x16x32_bf16(ahf[mf], bhf[nf], acc[mf][nf], 0, 0, 0);
                acc[mf][nf] = __builtin_amdgcn_mfma_f32_16x16x32_bf16(ahf[mf], blf[nf], acc[mf][nf], 0, 0, 0);
                acc[mf][nf] = __builtin_amdgcn_mfma_f32_16x16x32_bf16(alf[mf], bhf[nf], acc[mf][nf], 0, 0, 0);
            }
    }

    int gi = gi0 + wm * 64, gj = gj0 + wn * 64;
    int rbase = (lane >> 4) << 2;
    float sj[4];
#pragma unroll
    for (int nf = 0; nf < 4; ++nf) sj[nf] = sq[gj + nf * 16 + lr];

#pragma unroll
    for (int mf = 0; mf < 4; ++mf)
#pragma unroll
        for (int r = 0; r < 4; ++r) {
            int i = gi + mf * 16 + rbase + r;
            float si = sq[i];
#pragma unroll
            for (int nf = 0; nf < 4; ++nf) {
                int j = gj + nf * 16 + lr;
                if (j > i) {
                    float d = si + sj[nf] - 2.0f * acc[mf][nf][r];
                    if (d < t) {
                        unsigned p = atomicAdd(cnt, 1u);
                        if (p < (unsigned)CAP) edges[p] = make_int2(i, j);
                        atomicAdd(&deg[j], 1.0f);
                    }
                }
            }
        }
}

// ---------------- MFMA GEMM 64x64 tiles, counted-vmcnt pipeline ----------------
__global__ __launch_bounds__(256) void gemm_mfma_kernel(const unsigned short* __restrict__ A,
                                                        const unsigned short* __restrict__ Wt,
                                                        float* __restrict__ H, int Kp) {
    __shared__ __align__(16) unsigned short P[2][2][64][32];  // [buf][A/B] = 16 KB
    int bm = blockIdx.x, bn = blockIdx.y;
    int tid = threadIdx.x;
    int w = tid >> 6;
    int wm = w >> 1, wn = w & 1;      // 2x2 waves, 32x32 each
    int lane = tid & 63;
    int lr = lane & 15;
    int k2b = (lane >> 4) << 4;

    int gm0 = bm * 64, gn0 = bn * 64;

    const unsigned short* srcbase = (w < 2) ? A + (size_t)gm0 * Kp : Wt + (size_t)gn0 * Kp;
    int pidx = (w < 2) ? 0 : 1;
    int rowbase = (w & 1) * 32;
    int sr = lane >> 2;               // 0..15
    int ss = lane & 3;                // 0..3
    int kb = ((ss ^ ((sr >> 1) & 3)) << 4);

    auto STAGE = [&](int buf, int kc) {   // 2 global_load_lds per wave (vmcnt +2)
        char* dst = (char*)&P[buf][pidx][0][0] + rowbase * 64;
#pragma unroll
        for (int c = 0; c < 2; ++c) {
            int row = rowbase + c * 16 + sr;
            const char* g = (const char*)srcbase + ((size_t)row * Kp + kc) * 2 + kb;
            __builtin_amdgcn_global_load_lds((const void*)g, (void*)(dst + c * 1024), 16, 0, 0);
        }
    };

    f32x4 acc[2][2] = {};

    int nt = Kp / 32;
    STAGE(0, 0);
    STAGE(1, 32);
    for (int t = 0; t < nt; ++t) {
        const int c = t & 1;
        if (t < nt - 1) { asm volatile("s_waitcnt vmcnt(2)" ::: "memory"); }
        else            { asm volatile("s_waitcnt vmcnt(0)" ::: "memory"); }
        __builtin_amdgcn_sched_barrier(0);
        __builtin_amdgcn_s_barrier();
        const unsigned short* pA = &P[c][0][0][0];
        const unsigned short* pB = &P[c][1][0][0];
        bf16x8 af[2], bfr[2];
#pragma unroll
        for (int mf = 0; mf < 2; ++mf) af[mf] = frag_ld32(pA, wm * 32 + mf * 16 + lr, k2b);
#pragma unroll
        for (int nf = 0; nf < 2; ++nf) bfr[nf] = frag_ld32(pB, wn * 32 + nf * 16 + lr, k2b);
        __builtin_amdgcn_s_setprio(1);
#pragma unroll
        for (int mf = 0; mf < 2; ++mf)
#pragma unroll
            for (int nf = 0; nf < 2; ++nf)
                acc[mf][nf] = __builtin_amdgcn_mfma_f32_16x16x32_bf16(af[mf], bfr[nf], acc[mf][nf], 0, 0, 0);
        __builtin_amdgcn_s_setprio(0);
        asm volatile("s_waitcnt lgkmcnt(0)" ::: "memory");
        __builtin_amdgcn_sched_barrier(0);
        __builtin_amdgcn_s_barrier();
        if (t + 2 < nt) STAGE(c, (t + 2) * 32);
    }

    int rbase = (lane >> 4) << 2;
#pragma unroll
    for (int mf = 0; mf < 2; ++mf)
#pragma unroll
        for (int r = 0; r < 4; ++r) {
            int row = gm0 + wm * 32 + mf * 16 + rbase + r;
#pragma unroll
            for (int nf = 0; nf < 2; ++nf) {
                int col = gn0 + wn * 32 + nf * 16 + lr;
                H[(size_t)row * NH + col] = acc[mf][nf][r];
            }
        }
}

// ---------------- fused aggregate + bias + relu + bf16 cast + pool ----------------
#define ECAP 256
__global__ void relupool2_kernel(const float* __restrict__ H, const float* __restrict__ deg,
                                 const int2* __restrict__ edges, const unsigned* __restrict__ cnt,
                                 const float* __restrict__ b, unsigned short* __restrict__ Xb,
                                 float* __restrict__ psum) {
    __shared__ int lcnt;
    __shared__ int lsrc[ECAP];
    __shared__ short ltgt[ECAP];
    __shared__ float lw[ECAP];
    int f = threadIdx.x;
    int i0 = blockIdx.x * 64;
    if (f == 0) lcnt = 0;
    __syncthreads();
    unsigned n = *cnt;
    if (n > (unsigned)CAP) n = CAP;
    for (unsigned e = f; e < n; e += 256) {
        int2 ij = edges[e];
        if (ij.y >= i0 && ij.y < i0 + 64) {
            int p = atomicAdd(&lcnt, 1);
            if (p < ECAP) {
                lsrc[p] = ij.x;
                ltgt[p] = (short)(ij.y - i0);
                lw[p] = (1.0f / sqrtf(deg[ij.x])) * (1.0f / sqrtf(deg[ij.y]));
            }
        }
    }
    __syncthreads();
    int m = lcnt < ECAP ? lcnt : ECAP;
    float bias = b[f];
    float s = 0.f;
    for (int r = 0; r < 64; r++) {
        int row = i0 + r;
        float v = H[(size_t)row * NH + f] / deg[row];   // dinv^2 = 1/deg
        for (int p = 0; p < m; ++p)
            if (ltgt[p] == r) v += lw[p] * H[(size_t)lsrc[p] * NH + f];
        v = fmaxf(v + bias, 0.f);
        Xb[(size_t)row * NH + f] = f32_to_bf16(v);
        s += v;
    }
    atomicAdd(&psum[f], s);
}

__global__ void finalize_kernel(const float* __restrict__ psum, float* __restrict__ out) {
    int f = threadIdx.x;
    float p = (psum[f] + psum[NH + f] + psum[2 * NH + f]) * (1.0f / (float)N);
    out[f] = p;
    out[NH + f] = p;
}

static inline size_t align_up(size_t x, size_t a) { return (x + a - 1) & ~(a - 1); }

extern "C" void kernel_launch(void* const* d_in, const int* in_sizes, int n_in,
                              void* d_out, int out_size, void* d_ws, size_t ws_size,
                              hipStream_t stream) {
    const float* feature = (const float*)d_in[0];
    const float* W1 = (const float*)d_in[1];
    const float* b1 = (const float*)d_in[2];
    const float* W2 = (const float*)d_in[3];
    const float* b2 = (const float*)d_in[4];
    const float* W3 = (const float*)d_in[5];
    const float* b3 = (const float*)d_in[6];
    float* out = (float*)d_out;

    char* w = (char*)d_ws;
    size_t off = 0;
    float* sq = (float*)(w + off);         off += (size_t)N * 4;
    float* deg = (float*)(w + off);        off += (size_t)N * 4;
    float* psum = (float*)(w + off);       off += 3 * NH * 4;
    unsigned* tmax = (unsigned*)(w + off); off += 4;
    unsigned* cnt = (unsigned*)(w + off);  off += 4;
    off = align_up(off, 256);
    float* blockmin = (float*)(w + off);   off += (size_t)TRI2 * 4;
    off = align_up(off, 256);
    int2* edges = (int2*)(w + off);        off += (size_t)CAP * 8;
    off = align_up(off, 256);
    float* H = (float*)(w + off);          off += (size_t)N * NH * 4;
    off = align_up(off, 256);
    unsigned short* Xh = (unsigned short*)(w + off);  off += (size_t)N * K2 * 2;
    unsigned short* Xl = (unsigned short*)(w + off);  off += (size_t)N * K2 * 2;
    unsigned short* Wt1 = (unsigned short*)(w + off); off += (size_t)NH * K2 * 2;
    unsigned short* Wt2 = (unsigned short*)(w + off); off += (size_t)NH * NH * 2;
    unsigned short* Wt3 = (unsigned short*)(w + off); off += (size_t)NH * NH * 2;
    unsigned short* Xb = (unsigned short*)(w + off);  off += (size_t)N * NH * 2;

    prep_kernel<<<N + 3 * NH, 256, 0, stream>>>(feature, W1, W2, W3, Xh, Xl, sq, deg, psum,
                                                tmax, cnt, Wt1, Wt2, Wt3);
    distmax_kernel<<<TRI256, 512, 0, stream>>>(Xh, sq, tmax, blockmin);
    edges_kernel<<<TRI2, 256, 0, stream>>>(Xh, Xl, sq, tmax, blockmin, cnt, edges, deg);

    // layer 1
    gemm_mfma_kernel<<<dim3(N / 64, NH / 64), 256, 0, stream>>>(Xh, Wt1, H, K2);
    relupool2_kernel<<<N / 64, NH, 0, stream>>>(H, deg, edges, cnt, b1, Xb, psum);

    // layer 2
    gemm_mfma_kernel<<<dim3(N / 64, NH / 64), 256, 0, stream>>>(Xb, Wt2, H, NH);
    relupool2_kernel<<<N / 64, NH, 0, stream>>>(H, deg, edges, cnt, b2, Xb, psum + NH);

    // layer 3
    gemm_mfma_kernel<<<dim3(N / 64, NH / 64), 256, 0, stream>>>(Xb, Wt3, H, NH);
    relupool2_kernel<<<N / 64, NH, 0, stream>>>(H, deg, edges, cnt, b3, Xb, psum + 2 * NH);

    finalize_kernel<<<1, NH, 0, stream>>>(psum, out);
}